// Round 12
// baseline (265.232 us; speedup 1.0000x reference)
//
#include <hip/hip_runtime.h>
#include <math.h>

#define NUSER 2560
#define NITEM 3584
#define NN    6144
#define EDIM  64
#define NNZ   200000
#define DQK   256
#define KTOP  5
#define SPLITS 16
#define TPS    3          // 48 cand tiles / 16 splits
#define CK     8          // coarse candidates kept per (row, split); 16*8=128 rescored
#define ELLW   96         // padded-ELL row capacity
#define TPB   256
#define NBUILD 1563       // ceil(2*NNZ/256)
#define BSTR  72          // Bh LDS row stride in shorts

typedef __attribute__((ext_vector_type(8))) short bf16x8;
typedef __attribute__((ext_vector_type(4))) float f32x4;

__device__ __forceinline__ unsigned short f2bf(float f) {
    unsigned int b = __float_as_uint(f);
    unsigned int r = (b + 0x7FFFu + ((b >> 16) & 1u)) >> 16;
    return (unsigned short)r;
}
__device__ __forceinline__ int pack2(float a, float b) {
    return (int)f2bf(a) | ((int)f2bf(b) << 16);
}
__device__ __forceinline__ void ell_unpack(long long v, int* col, float* w) {
    *col = (int)(v & 0xffffffffLL);
    *w   = __int_as_float((int)(v >> 32));
}

// ================================================================ build (COO->ELL) + G = Wq^T Wk (1 extra block)
__global__ void build_kernel(const int* __restrict__ nr, const int* __restrict__ nc,
                             const float* __restrict__ nv,
                             const int* __restrict__ ar, const int* __restrict__ ac,
                             const float* __restrict__ Wq, const float* __restrict__ Wk,
                             const float* __restrict__ bq,
                             int* __restrict__ cnt_n, int* __restrict__ cnt_a,
                             long long* __restrict__ cv_n, int* __restrict__ cv_a,
                             float* __restrict__ Gbuf) {
    __shared__ float gq[4096];
    __shared__ float gk[4096];
    int t = threadIdx.x;

    if (blockIdx.x == NBUILD) {
        float accG[16];
#pragma unroll
        for (int i = 0; i < 16; ++i) accG[i] = 0.f;
        float uacc = 0.f;
        int e = t >> 2, fb = (t & 3) * 16;
        for (int d0 = 0; d0 < DQK; d0 += 64) {
            __syncthreads();
#pragma unroll
            for (int i = 0; i < 16; ++i) {
                int v = i * 256 + t;
                gq[v] = Wq[d0 * 64 + v];
                gk[v] = Wk[d0 * 64 + v];
            }
            __syncthreads();
            for (int dc = 0; dc < 64; ++dc) {
                float a = gq[dc * 64 + e];
                float4 w0 = *(const float4*)&gk[dc * 64 + fb];
                float4 w1 = *(const float4*)&gk[dc * 64 + fb + 4];
                float4 w2 = *(const float4*)&gk[dc * 64 + fb + 8];
                float4 w3 = *(const float4*)&gk[dc * 64 + fb + 12];
                accG[0]  = fmaf(a, w0.x, accG[0]);  accG[1]  = fmaf(a, w0.y, accG[1]);
                accG[2]  = fmaf(a, w0.z, accG[2]);  accG[3]  = fmaf(a, w0.w, accG[3]);
                accG[4]  = fmaf(a, w1.x, accG[4]);  accG[5]  = fmaf(a, w1.y, accG[5]);
                accG[6]  = fmaf(a, w1.z, accG[6]);  accG[7]  = fmaf(a, w1.w, accG[7]);
                accG[8]  = fmaf(a, w2.x, accG[8]);  accG[9]  = fmaf(a, w2.y, accG[9]);
                accG[10] = fmaf(a, w2.z, accG[10]); accG[11] = fmaf(a, w2.w, accG[11]);
                accG[12] = fmaf(a, w3.x, accG[12]); accG[13] = fmaf(a, w3.y, accG[13]);
                accG[14] = fmaf(a, w3.z, accG[14]); accG[15] = fmaf(a, w3.w, accG[15]);
            }
            if (t < 64) {
                for (int dc = 0; dc < 64; ++dc)
                    uacc = fmaf(bq[d0 + dc], gk[dc * 64 + t], uacc);
            }
        }
#pragma unroll
        for (int i = 0; i < 16; ++i) Gbuf[e * 64 + fb + i] = accG[i];
        if (t < 64) Gbuf[4096 + t] = uacc;
        return;
    }

    int g = blockIdx.x * TPB + t;
    if (g < NNZ) {
        int r = nr[g], c = nc[g];
        float v = nv[g];
        int slot = atomicAdd(&cnt_n[r], 1);
        long long pk = (unsigned int)c | ((long long)(unsigned int)__float_as_int(v) << 32);
        cv_n[r * ELLW + slot] = pk;
    } else if (g < 2 * NNZ) {
        int h = g - NNZ;
        int r = ar[h], c = ac[h];
        int slot = atomicAdd(&cnt_a[r], 1);
        cv_a[r * ELLW + slot] = c;
    }
}

// ================================================================ ELL SpMM, wave-per-row, x8 unroll
__global__ __launch_bounds__(TPB) void spmm_ell_emb_kernel(
        const int* __restrict__ cnt, const long long* __restrict__ cv,
        const float* __restrict__ user, const float* __restrict__ item,
        float* __restrict__ dst) {
    int r = blockIdx.x * 4 + (threadIdx.x >> 6);
    int lane = threadIdx.x & 63;
    int s = r * ELLW, e = s + cnt[r];
    float a[8];
#pragma unroll
    for (int u = 0; u < 8; ++u) a[u] = 0.f;
    int j = s, n8 = s + ((e - s) & ~7);
    for (; j < n8; j += 8) {
        int col[8]; float w[8];
#pragma unroll
        for (int u = 0; u < 8; ++u) ell_unpack(cv[j + u], &col[u], &w[u]);
#pragma unroll
        for (int u = 0; u < 8; ++u) {
            float x = (col[u] < NUSER) ? user[col[u] * EDIM + lane]
                                       : item[(col[u] - NUSER) * EDIM + lane];
            a[u] = fmaf(w[u], x, a[u]);
        }
    }
    for (; j < e; ++j) {
        int col; float w;
        ell_unpack(cv[j], &col, &w);
        float x = (col < NUSER) ? user[col * EDIM + lane] : item[(col - NUSER) * EDIM + lane];
        a[0] = fmaf(w, x, a[0]);
    }
    dst[r * EDIM + lane] = ((a[0] + a[1]) + (a[2] + a[3])) + ((a[4] + a[5]) + (a[6] + a[7]));
}

__global__ __launch_bounds__(TPB) void spmm_ell_kernel(
        const int* __restrict__ cnt, const long long* __restrict__ cv,
        const float* __restrict__ src, float* __restrict__ dst) {
    int r = blockIdx.x * 4 + (threadIdx.x >> 6);
    int lane = threadIdx.x & 63;
    int s = r * ELLW, e = s + cnt[r];
    float a[8];
#pragma unroll
    for (int u = 0; u < 8; ++u) a[u] = 0.f;
    int j = s, n8 = s + ((e - s) & ~7);
    for (; j < n8; j += 8) {
        int col[8]; float w[8];
#pragma unroll
        for (int u = 0; u < 8; ++u) ell_unpack(cv[j + u], &col[u], &w[u]);
#pragma unroll
        for (int u = 0; u < 8; ++u)
            a[u] = fmaf(w[u], src[col[u] * EDIM + lane], a[u]);
    }
    for (; j < e; ++j) {
        int col; float w;
        ell_unpack(cv[j], &col, &w);
        a[0] = fmaf(w, src[col * EDIM + lane], a[0]);
    }
    dst[r * EDIM + lane] = ((a[0] + a[1]) + (a[2] + a[3])) + ((a[4] + a[5]) + (a[6] + a[7]));
}

// Qm = ego2 + 0.5*(A@ego2) ; outmean = 0.5*(ego0+ego1) ; plus 96 P-blocks: P = ego2@G + u
__global__ __launch_bounds__(TPB) void qm_mean_kernel(
        const int* __restrict__ cnt, const int* __restrict__ cv,
        const float* __restrict__ ego2, const float* __restrict__ ego1,
        const float* __restrict__ user, const float* __restrict__ item,
        const float* __restrict__ Gbuf,
        float* __restrict__ Qm, float* __restrict__ outmean, float* __restrict__ P) {
    __shared__ float Gs[4160];
    int t = threadIdx.x;

    if (blockIdx.x >= NN / 4) {
        int pb = blockIdx.x - NN / 4;
#pragma unroll
        for (int i = 0; i < 17; ++i) {
            int v = i * 256 + t;
            if (v < 4160) Gs[v] = Gbuf[v];
        }
        __syncthreads();
        int r = pb * 64 + (t >> 2), fb = (t & 3) * 16;
        const float4* row4 = (const float4*)(ego2 + (size_t)r * EDIM);
        float4 rw[16];
#pragma unroll
        for (int i = 0; i < 16; ++i) rw[i] = row4[i];
        float4 acc0 = *(const float4*)&Gs[4096 + fb];
        float4 acc1 = *(const float4*)&Gs[4096 + fb + 4];
        float4 acc2 = *(const float4*)&Gs[4096 + fb + 8];
        float4 acc3 = *(const float4*)&Gs[4096 + fb + 12];
#pragma unroll
        for (int ee = 0; ee < 16; ++ee) {
            float av[4] = {rw[ee].x, rw[ee].y, rw[ee].z, rw[ee].w};
#pragma unroll
            for (int q = 0; q < 4; ++q) {
                int e = ee * 4 + q;
                float a = av[q];
                float4 g0 = *(const float4*)&Gs[e * 64 + fb];
                float4 g1 = *(const float4*)&Gs[e * 64 + fb + 4];
                float4 g2 = *(const float4*)&Gs[e * 64 + fb + 8];
                float4 g3 = *(const float4*)&Gs[e * 64 + fb + 12];
                acc0.x = fmaf(a, g0.x, acc0.x); acc0.y = fmaf(a, g0.y, acc0.y);
                acc0.z = fmaf(a, g0.z, acc0.z); acc0.w = fmaf(a, g0.w, acc0.w);
                acc1.x = fmaf(a, g1.x, acc1.x); acc1.y = fmaf(a, g1.y, acc1.y);
                acc1.z = fmaf(a, g1.z, acc1.z); acc1.w = fmaf(a, g1.w, acc1.w);
                acc2.x = fmaf(a, g2.x, acc2.x); acc2.y = fmaf(a, g2.y, acc2.y);
                acc2.z = fmaf(a, g2.z, acc2.z); acc2.w = fmaf(a, g2.w, acc2.w);
                acc3.x = fmaf(a, g3.x, acc3.x); acc3.y = fmaf(a, g3.y, acc3.y);
                acc3.z = fmaf(a, g3.z, acc3.z); acc3.w = fmaf(a, g3.w, acc3.w);
            }
        }
        float4* dst = (float4*)(P + (size_t)r * EDIM + fb);
        dst[0] = acc0; dst[1] = acc1; dst[2] = acc2; dst[3] = acc3;
        return;
    }

    int r = blockIdx.x * 4 + (t >> 6);
    int lane = t & 63;
    int s = r * ELLW, e = s + cnt[r];
    float a[8];
#pragma unroll
    for (int u = 0; u < 8; ++u) a[u] = 0.f;
    int j = s, n8 = s + ((e - s) & ~7);
    for (; j < n8; j += 8) {
        int col[8];
#pragma unroll
        for (int u = 0; u < 8; ++u) col[u] = cv[j + u];
#pragma unroll
        for (int u = 0; u < 8; ++u)
            a[u] += ego2[col[u] * EDIM + lane];
    }
    for (; j < e; ++j) a[0] += ego2[cv[j] * EDIM + lane];
    float acc = ((a[0] + a[1]) + (a[2] + a[3])) + ((a[4] + a[5]) + (a[6] + a[7]));
    int o = r * EDIM + lane;
    Qm[o] = ego2[o] + 0.5f * acc;
    float e0v = (r < NUSER) ? user[o] : item[o - NUSER * EDIM];
    outmean[o] = 0.5f * (e0v + ego1[o]);
}

// ================================================================ MFMA coarse top-8 (1536 blocks, 6 blk/CU)
__device__ __forceinline__ void ins3(float v, int ci, float tv[3], int ti[3]) {
    if (v > tv[2]) {
        bool p1 = v > tv[1], p0 = v > tv[0];
        tv[2] = p1 ? tv[1] : v;  ti[2] = p1 ? ti[1] : ci;
        if (p1) { tv[1] = p0 ? tv[0] : v; ti[1] = p0 ? ti[0] : ci; }
        if (p0) { tv[0] = v; ti[0] = ci; }
    }
}

__global__ __launch_bounds__(TPB, 6) void topk_kernel(
        const float* __restrict__ ego2, const float* __restrict__ Qm,
        int* __restrict__ pidx) {
    __shared__ __align__(16) short smem[13312];   // Ah 4096 + Bh 9216 shorts = 26.6 KB
    int t = threadIdx.x;
    int rb = blockIdx.x % 96, sp = blockIdx.x / 96;
    int r0 = rb * 64;
    int w = t >> 6, lane = t & 63, lq = lane >> 4, lc = lane & 15;

    short* Ah = smem;            // [64][64] bf16 row-major
    short* Bh = smem + 4096;     // [128][BSTR=72] bf16 padded

    { // stage A from fp32 Qm (once per block)
        int row = t >> 2, seg = t & 3;
        const float4* src = (const float4*)&Qm[(size_t)(r0 + row) * EDIM + seg * 16];
        float4 f0 = src[0], f1 = src[1], f2 = src[2], f3 = src[3];
        int4 p0, p1;
        p0.x = pack2(f0.x, f0.y); p0.y = pack2(f0.z, f0.w);
        p0.z = pack2(f1.x, f1.y); p0.w = pack2(f1.z, f1.w);
        p1.x = pack2(f2.x, f2.y); p1.y = pack2(f2.z, f2.w);
        p1.z = pack2(f3.x, f3.y); p1.w = pack2(f3.z, f3.w);
        *(int4*)&Ah[row * EDIM + seg * 16] = p0;
        *(int4*)&Ah[row * EDIM + seg * 16 + 8] = p1;
    }

    float4 pa[4], pb[4];
    { // prefetch tile 0 (fp32)
        int c0 = (sp * TPS) * 128;
#pragma unroll
        for (int rep = 0; rep < 4; ++rep) {
            int v = t + 256 * rep;
            const float4* src = (const float4*)&ego2[(size_t)(c0 + (v >> 3)) * EDIM + (v & 7) * 8];
            pa[rep] = src[0]; pb[rep] = src[1];
        }
    }

    float t3v[4][3]; int t3i[4][3];
#pragma unroll
    for (int i = 0; i < 4; ++i)
#pragma unroll
        for (int k = 0; k < 3; ++k) { t3v[i][k] = -INFINITY; t3i[i][k] = 0x7fffffff; }

    bf16x8 af0, af1;
    for (int tile = 0; tile < TPS; ++tile) {
        int c0 = (sp * TPS + tile) * 128;
        __syncthreads();
        {
#pragma unroll
            for (int rep = 0; rep < 4; ++rep) {
                int v = t + 256 * rep;
                int4 q;
                q.x = pack2(pa[rep].x, pa[rep].y); q.y = pack2(pa[rep].z, pa[rep].w);
                q.z = pack2(pb[rep].x, pb[rep].y); q.w = pack2(pb[rep].z, pb[rep].w);
                *(int4*)&Bh[(v >> 3) * BSTR + (v & 7) * 8] = q;
            }
        }
        if (tile + 1 < TPS) {
            int c1 = c0 + 128;
#pragma unroll
            for (int rep = 0; rep < 4; ++rep) {
                int v = t + 256 * rep;
                const float4* src = (const float4*)&ego2[(size_t)(c1 + (v >> 3)) * EDIM + (v & 7) * 8];
                pa[rep] = src[0]; pb[rep] = src[1];
            }
        }
        __syncthreads();
        if (tile == 0) {
            af0 = *(const bf16x8*)&Ah[(w * 16 + lc) * EDIM + lq * 8];
            af1 = *(const bf16x8*)&Ah[(w * 16 + lc) * EDIM + 32 + lq * 8];
        }

#pragma unroll
        for (int ch = 0; ch < 8; ++ch) {
            bf16x8 b0 = *(const bf16x8*)&Bh[(ch * 16 + lc) * BSTR + lq * 8];
            bf16x8 b1 = *(const bf16x8*)&Bh[(ch * 16 + lc) * BSTR + 32 + lq * 8];
            f32x4 acc = {0.f, 0.f, 0.f, 0.f};
            acc = __builtin_amdgcn_mfma_f32_16x16x32_bf16(af0, b0, acc, 0, 0, 0);
            acc = __builtin_amdgcn_mfma_f32_16x16x32_bf16(af1, b1, acc, 0, 0, 0);
            int ci = c0 + ch * 16 + lc;
#pragma unroll
            for (int reg = 0; reg < 4; ++reg)
                ins3(acc[reg], ci, t3v[reg], t3i[reg]);
        }
    }

#pragma unroll
    for (int i = 0; i < 4; ++i) {
        int row = r0 + w * 16 + lq * 4 + i;
        int ptr = 0;
        for (int k = 0; k < CK; ++k) {
            float cvv = (ptr == 0) ? t3v[i][0] : (ptr == 1) ? t3v[i][1]
                      : (ptr == 2) ? t3v[i][2] : -INFINITY;
            int   cii = (ptr == 0) ? t3i[i][0] : (ptr == 1) ? t3i[i][1]
                      : (ptr == 2) ? t3i[i][2] : 0x7fffffff;
            float bv = cvv; int bi = cii;
#pragma unroll
            for (int off = 1; off < 16; off <<= 1) {
                float ov = __shfl_xor(bv, off, 64);
                int   oi = __shfl_xor(bi, off, 64);
                if (ov > bv || (ov == bv && oi < bi)) { bv = ov; bi = oi; }
            }
            if (bv == cvv && bi == cii) ptr++;
            if (lc == 0) pidx[(row * SPLITS + sp) * CK + k] = bi;
        }
    }
}

// ================================================================ rescore(128) + top-5 + softmax + fused Wv out
__global__ __launch_bounds__(TPB) void attn_sel_kernel(
        const float* __restrict__ Qm, const float* __restrict__ P,
        const float* __restrict__ ego2, const int* __restrict__ pidx,
        const float* __restrict__ Wv, const float* __restrict__ bv_,
        float* __restrict__ out) {
    __shared__ float sb[4][128];
    __shared__ float sa[4][128];
    int wv = threadIdx.x >> 6, lane = threadIdx.x & 63;
    int r = blockIdx.x * 4 + wv;
    int ci0 = pidx[r * 128 + lane];
    int ci1 = pidx[r * 128 + 64 + lane];
    int part = lane & 3;

    const float4* qmp = (const float4*)(Qm + (size_t)r * EDIM + part * 16);
    float4 q0 = qmp[0], q1 = qmp[1], q2 = qmp[2], q3 = qmp[3];
    const float4* pmp = (const float4*)(P + (size_t)r * EDIM + part * 16);
    float4 p0 = pmp[0], p1 = pmp[1], p2 = pmp[2], p3 = pmp[3];

    // rescore 128 cands: quad-per-cand, coalesced 4-lane row reads, quad shuffle-reduce
#pragma unroll
    for (int p = 0; p < 8; ++p) {
        int j = p * 16 + (lane >> 2);                 // 0..127
        int c = (j < 64) ? __shfl(ci0, j, 64) : __shfl(ci1, j - 64, 64);
        const float4* ep = (const float4*)(ego2 + (size_t)c * EDIM + part * 16);
        float4 e0 = ep[0], e1 = ep[1], e2 = ep[2], e3 = ep[3];
        float s = 0.f, s2 = 0.f;
        s = fmaf(q0.x, e0.x, s); s = fmaf(q0.y, e0.y, s); s = fmaf(q0.z, e0.z, s); s = fmaf(q0.w, e0.w, s);
        s = fmaf(q1.x, e1.x, s); s = fmaf(q1.y, e1.y, s); s = fmaf(q1.z, e1.z, s); s = fmaf(q1.w, e1.w, s);
        s = fmaf(q2.x, e2.x, s); s = fmaf(q2.y, e2.y, s); s = fmaf(q2.z, e2.z, s); s = fmaf(q2.w, e2.w, s);
        s = fmaf(q3.x, e3.x, s); s = fmaf(q3.y, e3.y, s); s = fmaf(q3.z, e3.z, s); s = fmaf(q3.w, e3.w, s);
        s2 = fmaf(p0.x, e0.x, s2); s2 = fmaf(p0.y, e0.y, s2); s2 = fmaf(p0.z, e0.z, s2); s2 = fmaf(p0.w, e0.w, s2);
        s2 = fmaf(p1.x, e1.x, s2); s2 = fmaf(p1.y, e1.y, s2); s2 = fmaf(p1.z, e1.z, s2); s2 = fmaf(p1.w, e1.w, s2);
        s2 = fmaf(p2.x, e2.x, s2); s2 = fmaf(p2.y, e2.y, s2); s2 = fmaf(p2.z, e2.z, s2); s2 = fmaf(p2.w, e2.w, s2);
        s2 = fmaf(p3.x, e3.x, s2); s2 = fmaf(p3.y, e3.y, s2); s2 = fmaf(p3.z, e3.z, s2); s2 = fmaf(p3.w, e3.w, s2);
        s  += __shfl_xor(s, 1, 64);  s  += __shfl_xor(s, 2, 64);
        s2 += __shfl_xor(s2, 1, 64); s2 += __shfl_xor(s2, 2, 64);
        if (part == 0) { sb[wv][j] = s; sa[wv][j] = s2; }
    }
    float sv0 = sb[wv][lane],      av0 = sa[wv][lane];
    float sv1 = sb[wv][64 + lane], av1 = sa[wv][64 + lane];

    // top-5 over 128 via two-local admissible argmax (R2-validated pattern) + payload
    float prevv = INFINITY; int previ = -1;
    int cI[KTOP]; float atk[KTOP];
#pragma unroll
    for (int k = 0; k < KTOP; ++k) {
        bool adm0 = (sv0 < prevv) || (sv0 == prevv && ci0 > previ);
        bool adm1 = (sv1 < prevv) || (sv1 == prevv && ci1 > previ);
        float bv = adm0 ? sv0 : -INFINITY;
        int   bi = adm0 ? ci0 : 0x7fffffff;
        float ba = av0;
        if (adm1 && (sv1 > bv || (sv1 == bv && ci1 < bi))) { bv = sv1; bi = ci1; ba = av1; }
#pragma unroll
        for (int off = 1; off < 64; off <<= 1) {
            float ov = __shfl_xor(bv, off, 64);
            int   oi = __shfl_xor(bi, off, 64);
            float oa = __shfl_xor(ba, off, 64);
            if (ov > bv || (ov == bv && oi < bi)) { bv = ov; bi = oi; ba = oa; }
        }
        cI[k] = bi; atk[k] = ba; prevv = bv; previ = bi;
    }

    float sc[KTOP];
#pragma unroll
    for (int k = 0; k < KTOP; ++k) sc[k] = atk[k] * 0.0625f;   // 1/sqrt(256)
    float mx = sc[0];
#pragma unroll
    for (int k = 1; k < KTOP; ++k) mx = fmaxf(mx, sc[k]);
    float wgt[KTOP], ssum = 0.f;
#pragma unroll
    for (int k = 0; k < KTOP; ++k) { wgt[k] = expf(sc[k] - mx); ssum += wgt[k]; }
    float inv = 1.f / ssum;

    // m[e] (lane = e), then fused out[r][d] = bv[d] + sum_e Wv[d][e]*m[e], d = lane*4..+3
    float mm = 0.f;
#pragma unroll
    for (int k = 0; k < KTOP; ++k)
        mm = fmaf(wgt[k] * inv, ego2[(size_t)cI[k] * EDIM + lane], mm);

    int d0 = lane * 4;
    float4 oacc = *(const float4*)&bv_[d0];
    for (int e0 = 0; e0 < 64; e0 += 4) {
        float m0 = __shfl(mm, e0, 64), m1 = __shfl(mm, e0 + 1, 64);
        float m2 = __shfl(mm, e0 + 2, 64), m3 = __shfl(mm, e0 + 3, 64);
        float4 w0 = *(const float4*)&Wv[(d0 + 0) * EDIM + e0];
        float4 w1 = *(const float4*)&Wv[(d0 + 1) * EDIM + e0];
        float4 w2 = *(const float4*)&Wv[(d0 + 2) * EDIM + e0];
        float4 w3 = *(const float4*)&Wv[(d0 + 3) * EDIM + e0];
        oacc.x = fmaf(m0, w0.x, oacc.x); oacc.x = fmaf(m1, w0.y, oacc.x);
        oacc.x = fmaf(m2, w0.z, oacc.x); oacc.x = fmaf(m3, w0.w, oacc.x);
        oacc.y = fmaf(m0, w1.x, oacc.y); oacc.y = fmaf(m1, w1.y, oacc.y);
        oacc.y = fmaf(m2, w1.z, oacc.y); oacc.y = fmaf(m3, w1.w, oacc.y);
        oacc.z = fmaf(m0, w2.x, oacc.z); oacc.z = fmaf(m1, w2.y, oacc.z);
        oacc.z = fmaf(m2, w2.z, oacc.z); oacc.z = fmaf(m3, w2.w, oacc.z);
        oacc.w = fmaf(m0, w3.x, oacc.w); oacc.w = fmaf(m1, w3.y, oacc.w);
        oacc.w = fmaf(m2, w3.z, oacc.w); oacc.w = fmaf(m3, w3.w, oacc.w);
    }
    *(float4*)&out[(size_t)r * DQK + d0] = oacc;
}

// ================================================================ launch
extern "C" void kernel_launch(void* const* d_in, const int* in_sizes, int n_in,
                              void* d_out, int out_size, void* d_ws, size_t ws_size,
                              hipStream_t stream) {
    const float* user  = (const float*)d_in[0];
    const float* item  = (const float*)d_in[1];
    const int*   nrows = (const int*)d_in[2];
    const int*   ncols = (const int*)d_in[3];
    const float* nvals = (const float*)d_in[4];
    const int*   arows = (const int*)d_in[5];
    const int*   acols = (const int*)d_in[6];
    const float* Wq = (const float*)d_in[8];  const float* bq = (const float*)d_in[9];
    const float* Wk = (const float*)d_in[10];
    const float* Wv = (const float*)d_in[12]; const float* bvp = (const float*)d_in[13];
    float* out = (float*)d_out;
    float* ws  = (float*)d_ws;

    const int NE = NN * EDIM;              // 393216
    float* ego1 = ws;
    float* ego2 = ws + NE;
    float* Qm   = ws + 2 * NE;
    float* P    = ws + 3 * NE;
    int*   pidx = (int*)(ws + 4 * NE);     // NN*128 ints = 2*NE
    float* Gbuf = ws + 6 * NE;             // 4160 floats
    int*   ell  = (int*)(ws + 6 * NE + 4160);
    int* cnt_n  = ell;                     // 6144
    int* cnt_a  = ell + 6144;              // 6144
    long long* cv_n = (long long*)(ell + 12288);   // NN*ELLW x 8B
    int* cv_a   = (int*)(cv_n + NN * ELLW);        // NN*ELLW x 4B

    hipMemsetAsync(cnt_n, 0, 12288 * sizeof(int), stream);
    build_kernel<<<NBUILD + 1, TPB, 0, stream>>>(nrows, ncols, nvals, arows, acols,
                                                 Wq, Wk, bq,
                                                 cnt_n, cnt_a, cv_n, cv_a, Gbuf);
    spmm_ell_emb_kernel<<<NN / 4, TPB, 0, stream>>>(cnt_n, cv_n, user, item, ego1);
    spmm_ell_kernel<<<NN / 4, TPB, 0, stream>>>(cnt_n, cv_n, ego1, ego2);
    qm_mean_kernel<<<NN / 4 + 96, TPB, 0, stream>>>(cnt_a, cv_a, ego2, ego1, user, item,
                                                    Gbuf, Qm, out, P);
    topk_kernel<<<96 * SPLITS, TPB, 0, stream>>>(ego2, Qm, pidx);
    attn_sel_kernel<<<NN / 4, TPB, 0, stream>>>(Qm, P, ego2, pidx, Wv, bvp, out + NE);
}

// Round 13
// 224.605 us; speedup vs baseline: 1.1809x; 1.1809x over previous
//
#include <hip/hip_runtime.h>
#include <math.h>

#define NUSER 2560
#define NITEM 3584
#define NN    6144
#define EDIM  64
#define NNZ   200000
#define DQK   256
#define KTOP  5
#define SPLITS 16
#define TPS    3          // 48 cand tiles / 16 splits
#define CK     8          // coarse per (row,split); 16*8=128 rescored
#define ELLW   96
#define TPB   256
#define NBUILD 1563       // ceil(2*NNZ/256)
#define BSTR  72

typedef __attribute__((ext_vector_type(8))) short bf16x8;
typedef __attribute__((ext_vector_type(4))) float f32x4;

__device__ __forceinline__ unsigned short f2bf(float f) {
    unsigned int b = __float_as_uint(f);
    unsigned int r = (b + 0x7FFFu + ((b >> 16) & 1u)) >> 16;
    return (unsigned short)r;
}
__device__ __forceinline__ int pack2(float a, float b) {
    return (int)f2bf(a) | ((int)f2bf(b) << 16);
}
__device__ __forceinline__ void ell_unpack(long long v, int* col, float* w) {
    *col = (int)(v & 0xffffffffLL);
    *w   = __int_as_float((int)(v >> 32));
}

// ================================================================ build (COO->ELL) + G spread over 17 blocks
__global__ void build_kernel(const int* __restrict__ nr, const int* __restrict__ nc,
                             const float* __restrict__ nv,
                             const int* __restrict__ ar, const int* __restrict__ ac,
                             const float* __restrict__ Wq, const float* __restrict__ Wk,
                             const float* __restrict__ bq,
                             int* __restrict__ cnt_n, int* __restrict__ cnt_a,
                             long long* __restrict__ cv_n, int* __restrict__ cv_a,
                             float* __restrict__ Gbuf) {
    int t = threadIdx.x;

    if (blockIdx.x >= NBUILD) {
        int gb = blockIdx.x - NBUILD;
        if (gb < 16) {
            // G[e][f] = sum_d Wq[d][e]*Wk[d][f]; block gb handles e in [gb*4, gb*4+4)
            int ei = gb * 4 + (t >> 6);     // uniform per wave
            int f  = t & 63;
            float a8[8];
#pragma unroll
            for (int u = 0; u < 8; ++u) a8[u] = 0.f;
            for (int d0 = 0; d0 < DQK; d0 += 8) {
#pragma unroll
                for (int u = 0; u < 8; ++u)
                    a8[u] = fmaf(Wq[(d0 + u) * 64 + ei], Wk[(d0 + u) * 64 + f], a8[u]);
            }
            Gbuf[ei * 64 + f] = ((a8[0] + a8[1]) + (a8[2] + a8[3]))
                              + ((a8[4] + a8[5]) + (a8[6] + a8[7]));
        } else {
            // u[f] = sum_d bq[d]*Wk[d][f]
            __shared__ float sm[256];
            int f = t & 63, dq = t >> 6;
            float p = 0.f;
            for (int d = dq * 64; d < dq * 64 + 64; ++d)
                p = fmaf(bq[d], Wk[d * 64 + f], p);
            sm[t] = p;
            __syncthreads();
            if (t < 64) Gbuf[4096 + t] = ((sm[t] + sm[64 + t]) + (sm[128 + t] + sm[192 + t]));
        }
        return;
    }

    int g = blockIdx.x * TPB + t;
    if (g < NNZ) {
        int r = nr[g], c = nc[g];
        float v = nv[g];
        int slot = atomicAdd(&cnt_n[r], 1);
        long long pk = (unsigned int)c | ((long long)(unsigned int)__float_as_int(v) << 32);
        cv_n[r * ELLW + slot] = pk;
    } else if (g < 2 * NNZ) {
        int h = g - NNZ;
        int r = ar[h], c = ac[h];
        int slot = atomicAdd(&cnt_a[r], 1);
        cv_a[r * ELLW + slot] = c;
    }
}

// ================================================================ ELL SpMM, wave-per-row, x8 unroll
__global__ __launch_bounds__(TPB) void spmm_ell_emb_kernel(
        const int* __restrict__ cnt, const long long* __restrict__ cv,
        const float* __restrict__ user, const float* __restrict__ item,
        float* __restrict__ dst) {
    int r = blockIdx.x * 4 + (threadIdx.x >> 6);
    int lane = threadIdx.x & 63;
    int s = r * ELLW, e = s + cnt[r];
    float a[8];
#pragma unroll
    for (int u = 0; u < 8; ++u) a[u] = 0.f;
    int j = s, n8 = s + ((e - s) & ~7);
    for (; j < n8; j += 8) {
        int col[8]; float w[8];
#pragma unroll
        for (int u = 0; u < 8; ++u) ell_unpack(cv[j + u], &col[u], &w[u]);
#pragma unroll
        for (int u = 0; u < 8; ++u) {
            float x = (col[u] < NUSER) ? user[col[u] * EDIM + lane]
                                       : item[(col[u] - NUSER) * EDIM + lane];
            a[u] = fmaf(w[u], x, a[u]);
        }
    }
    for (; j < e; ++j) {
        int col; float w;
        ell_unpack(cv[j], &col, &w);
        float x = (col < NUSER) ? user[col * EDIM + lane] : item[(col - NUSER) * EDIM + lane];
        a[0] = fmaf(w, x, a[0]);
    }
    dst[r * EDIM + lane] = ((a[0] + a[1]) + (a[2] + a[3])) + ((a[4] + a[5]) + (a[6] + a[7]));
}

__global__ __launch_bounds__(TPB) void spmm_ell_kernel(
        const int* __restrict__ cnt, const long long* __restrict__ cv,
        const float* __restrict__ src, float* __restrict__ dst) {
    int r = blockIdx.x * 4 + (threadIdx.x >> 6);
    int lane = threadIdx.x & 63;
    int s = r * ELLW, e = s + cnt[r];
    float a[8];
#pragma unroll
    for (int u = 0; u < 8; ++u) a[u] = 0.f;
    int j = s, n8 = s + ((e - s) & ~7);
    for (; j < n8; j += 8) {
        int col[8]; float w[8];
#pragma unroll
        for (int u = 0; u < 8; ++u) ell_unpack(cv[j + u], &col[u], &w[u]);
#pragma unroll
        for (int u = 0; u < 8; ++u)
            a[u] = fmaf(w[u], src[col[u] * EDIM + lane], a[u]);
    }
    for (; j < e; ++j) {
        int col; float w;
        ell_unpack(cv[j], &col, &w);
        a[0] = fmaf(w, src[col * EDIM + lane], a[0]);
    }
    dst[r * EDIM + lane] = ((a[0] + a[1]) + (a[2] + a[3])) + ((a[4] + a[5]) + (a[6] + a[7]));
}

// Qm = ego2 + 0.5*(A@ego2) ; outmean = 0.5*(ego0+ego1) ; plus 96 P-blocks: P = ego2@G + u
__global__ __launch_bounds__(TPB) void qm_mean_kernel(
        const int* __restrict__ cnt, const int* __restrict__ cv,
        const float* __restrict__ ego2, const float* __restrict__ ego1,
        const float* __restrict__ user, const float* __restrict__ item,
        const float* __restrict__ Gbuf,
        float* __restrict__ Qm, float* __restrict__ outmean, float* __restrict__ P) {
    __shared__ float Gs[4160];
    int t = threadIdx.x;

    if (blockIdx.x >= NN / 4) {
        int pb = blockIdx.x - NN / 4;
#pragma unroll
        for (int i = 0; i < 17; ++i) {
            int v = i * 256 + t;
            if (v < 4160) Gs[v] = Gbuf[v];
        }
        __syncthreads();
        int r = pb * 64 + (t >> 2), fb = (t & 3) * 16;
        const float4* row4 = (const float4*)(ego2 + (size_t)r * EDIM);
        float4 rw[16];
#pragma unroll
        for (int i = 0; i < 16; ++i) rw[i] = row4[i];
        float4 acc0 = *(const float4*)&Gs[4096 + fb];
        float4 acc1 = *(const float4*)&Gs[4096 + fb + 4];
        float4 acc2 = *(const float4*)&Gs[4096 + fb + 8];
        float4 acc3 = *(const float4*)&Gs[4096 + fb + 12];
#pragma unroll
        for (int ee = 0; ee < 16; ++ee) {
            float av[4] = {rw[ee].x, rw[ee].y, rw[ee].z, rw[ee].w};
#pragma unroll
            for (int q = 0; q < 4; ++q) {
                int e = ee * 4 + q;
                float a = av[q];
                float4 g0 = *(const float4*)&Gs[e * 64 + fb];
                float4 g1 = *(const float4*)&Gs[e * 64 + fb + 4];
                float4 g2 = *(const float4*)&Gs[e * 64 + fb + 8];
                float4 g3 = *(const float4*)&Gs[e * 64 + fb + 12];
                acc0.x = fmaf(a, g0.x, acc0.x); acc0.y = fmaf(a, g0.y, acc0.y);
                acc0.z = fmaf(a, g0.z, acc0.z); acc0.w = fmaf(a, g0.w, acc0.w);
                acc1.x = fmaf(a, g1.x, acc1.x); acc1.y = fmaf(a, g1.y, acc1.y);
                acc1.z = fmaf(a, g1.z, acc1.z); acc1.w = fmaf(a, g1.w, acc1.w);
                acc2.x = fmaf(a, g2.x, acc2.x); acc2.y = fmaf(a, g2.y, acc2.y);
                acc2.z = fmaf(a, g2.z, acc2.z); acc2.w = fmaf(a, g2.w, acc2.w);
                acc3.x = fmaf(a, g3.x, acc3.x); acc3.y = fmaf(a, g3.y, acc3.y);
                acc3.z = fmaf(a, g3.z, acc3.z); acc3.w = fmaf(a, g3.w, acc3.w);
            }
        }
        float4* dst = (float4*)(P + (size_t)r * EDIM + fb);
        dst[0] = acc0; dst[1] = acc1; dst[2] = acc2; dst[3] = acc3;
        return;
    }

    int r = blockIdx.x * 4 + (t >> 6);
    int lane = t & 63;
    int s = r * ELLW, e = s + cnt[r];
    float a[8];
#pragma unroll
    for (int u = 0; u < 8; ++u) a[u] = 0.f;
    int j = s, n8 = s + ((e - s) & ~7);
    for (; j < n8; j += 8) {
        int col[8];
#pragma unroll
        for (int u = 0; u < 8; ++u) col[u] = cv[j + u];
#pragma unroll
        for (int u = 0; u < 8; ++u)
            a[u] += ego2[col[u] * EDIM + lane];
    }
    for (; j < e; ++j) a[0] += ego2[cv[j] * EDIM + lane];
    float acc = ((a[0] + a[1]) + (a[2] + a[3])) + ((a[4] + a[5]) + (a[6] + a[7]));
    int o = r * EDIM + lane;
    Qm[o] = ego2[o] + 0.5f * acc;
    float e0v = (r < NUSER) ? user[o] : item[o - NUSER * EDIM];
    outmean[o] = 0.5f * (e0v + ego1[o]);
}

// ================================================================ MFMA coarse top-8 (1536 blocks, 6 blk/CU)
__device__ __forceinline__ void ins3(float v, int ci, float tv[3], int ti[3]) {
    if (v > tv[2]) {
        bool p1 = v > tv[1], p0 = v > tv[0];
        tv[2] = p1 ? tv[1] : v;  ti[2] = p1 ? ti[1] : ci;
        if (p1) { tv[1] = p0 ? tv[0] : v; ti[1] = p0 ? ti[0] : ci; }
        if (p0) { tv[0] = v; ti[0] = ci; }
    }
}

__global__ __launch_bounds__(TPB, 6) void topk_kernel(
        const float* __restrict__ ego2, const float* __restrict__ Qm,
        int* __restrict__ pidx) {
    __shared__ __align__(16) short smem[13312];   // Ah 4096 + Bh 9216 shorts = 26.6 KB
    int t = threadIdx.x;
    int rb = blockIdx.x % 96, sp = blockIdx.x / 96;
    int r0 = rb * 64;
    int w = t >> 6, lane = t & 63, lq = lane >> 4, lc = lane & 15;

    short* Ah = smem;            // [64][64] bf16 row-major
    short* Bh = smem + 4096;     // [128][BSTR=72] bf16 padded

    { // stage A from fp32 Qm (once per block)
        int row = t >> 2, seg = t & 3;
        const float4* src = (const float4*)&Qm[(size_t)(r0 + row) * EDIM + seg * 16];
        float4 f0 = src[0], f1 = src[1], f2 = src[2], f3 = src[3];
        int4 p0, p1;
        p0.x = pack2(f0.x, f0.y); p0.y = pack2(f0.z, f0.w);
        p0.z = pack2(f1.x, f1.y); p0.w = pack2(f1.z, f1.w);
        p1.x = pack2(f2.x, f2.y); p1.y = pack2(f2.z, f2.w);
        p1.z = pack2(f3.x, f3.y); p1.w = pack2(f3.z, f3.w);
        *(int4*)&Ah[row * EDIM + seg * 16] = p0;
        *(int4*)&Ah[row * EDIM + seg * 16 + 8] = p1;
    }

    float4 pa[4], pb[4];
    { // prefetch tile 0 (fp32)
        int c0 = (sp * TPS) * 128;
#pragma unroll
        for (int rep = 0; rep < 4; ++rep) {
            int v = t + 256 * rep;
            const float4* src = (const float4*)&ego2[(size_t)(c0 + (v >> 3)) * EDIM + (v & 7) * 8];
            pa[rep] = src[0]; pb[rep] = src[1];
        }
    }

    float t3v[4][3]; int t3i[4][3];
#pragma unroll
    for (int i = 0; i < 4; ++i)
#pragma unroll
        for (int k = 0; k < 3; ++k) { t3v[i][k] = -INFINITY; t3i[i][k] = 0x7fffffff; }

    bf16x8 af0, af1;
    for (int tile = 0; tile < TPS; ++tile) {
        int c0 = (sp * TPS + tile) * 128;
        __syncthreads();
        {
#pragma unroll
            for (int rep = 0; rep < 4; ++rep) {
                int v = t + 256 * rep;
                int4 q;
                q.x = pack2(pa[rep].x, pa[rep].y); q.y = pack2(pa[rep].z, pa[rep].w);
                q.z = pack2(pb[rep].x, pb[rep].y); q.w = pack2(pb[rep].z, pb[rep].w);
                *(int4*)&Bh[(v >> 3) * BSTR + (v & 7) * 8] = q;
            }
        }
        if (tile + 1 < TPS) {
            int c1 = c0 + 128;
#pragma unroll
            for (int rep = 0; rep < 4; ++rep) {
                int v = t + 256 * rep;
                const float4* src = (const float4*)&ego2[(size_t)(c1 + (v >> 3)) * EDIM + (v & 7) * 8];
                pa[rep] = src[0]; pb[rep] = src[1];
            }
        }
        __syncthreads();
        if (tile == 0) {
            af0 = *(const bf16x8*)&Ah[(w * 16 + lc) * EDIM + lq * 8];
            af1 = *(const bf16x8*)&Ah[(w * 16 + lc) * EDIM + 32 + lq * 8];
        }

#pragma unroll
        for (int ch = 0; ch < 8; ++ch) {
            bf16x8 b0 = *(const bf16x8*)&Bh[(ch * 16 + lc) * BSTR + lq * 8];
            bf16x8 b1 = *(const bf16x8*)&Bh[(ch * 16 + lc) * BSTR + 32 + lq * 8];
            f32x4 acc = {0.f, 0.f, 0.f, 0.f};
            acc = __builtin_amdgcn_mfma_f32_16x16x32_bf16(af0, b0, acc, 0, 0, 0);
            acc = __builtin_amdgcn_mfma_f32_16x16x32_bf16(af1, b1, acc, 0, 0, 0);
            int ci = c0 + ch * 16 + lc;
#pragma unroll
            for (int reg = 0; reg < 4; ++reg)
                ins3(acc[reg], ci, t3v[reg], t3i[reg]);
        }
    }

#pragma unroll
    for (int i = 0; i < 4; ++i) {
        int row = r0 + w * 16 + lq * 4 + i;
        int ptr = 0;
        for (int k = 0; k < CK; ++k) {
            float cvv = (ptr == 0) ? t3v[i][0] : (ptr == 1) ? t3v[i][1]
                      : (ptr == 2) ? t3v[i][2] : -INFINITY;
            int   cii = (ptr == 0) ? t3i[i][0] : (ptr == 1) ? t3i[i][1]
                      : (ptr == 2) ? t3i[i][2] : 0x7fffffff;
            float bv = cvv; int bi = cii;
#pragma unroll
            for (int off = 1; off < 16; off <<= 1) {
                float ov = __shfl_xor(bv, off, 64);
                int   oi = __shfl_xor(bi, off, 64);
                if (ov > bv || (ov == bv && oi < bi)) { bv = ov; bi = oi; }
            }
            if (bv == cvv && bi == cii) ptr++;
            if (lc == 0) pidx[(row * SPLITS + sp) * CK + k] = bi;
        }
    }
}

// ================================================================ rescore(128) + top-5 + softmax + WvT-staged out
__global__ __launch_bounds__(TPB) void attn_sel_kernel(
        const float* __restrict__ Qm, const float* __restrict__ P,
        const float* __restrict__ ego2, const int* __restrict__ pidx,
        const float* __restrict__ Wv, const float* __restrict__ bv_,
        float* __restrict__ out) {
    __shared__ float sb[4][128];
    __shared__ float sa[4][128];
    __shared__ float smm[4][64];
    __shared__ float WvT[64 * 130];     // [e][d-half] padded, 33.3 KB
    int wv = threadIdx.x >> 6, lane = threadIdx.x & 63;
    int t = threadIdx.x;
    int r = blockIdx.x * 4 + wv;
    int ci0 = pidx[r * 128 + lane];
    int ci1 = pidx[r * 128 + 64 + lane];
    int part = lane & 3;

    const float4* qmp = (const float4*)(Qm + (size_t)r * EDIM + part * 16);
    float4 q0 = qmp[0], q1 = qmp[1], q2 = qmp[2], q3 = qmp[3];
    const float4* pmp = (const float4*)(P + (size_t)r * EDIM + part * 16);
    float4 p0 = pmp[0], p1 = pmp[1], p2 = pmp[2], p3 = pmp[3];

    // rescore 128 cands: quad-per-cand, coalesced 4-lane row reads, quad shuffle-reduce
#pragma unroll
    for (int p = 0; p < 8; ++p) {
        int j = p * 16 + (lane >> 2);                 // 0..127
        int c = (j < 64) ? __shfl(ci0, j, 64) : __shfl(ci1, j - 64, 64);
        const float4* ep = (const float4*)(ego2 + (size_t)c * EDIM + part * 16);
        float4 e0 = ep[0], e1 = ep[1], e2 = ep[2], e3 = ep[3];
        float s = 0.f, s2 = 0.f;
        s = fmaf(q0.x, e0.x, s); s = fmaf(q0.y, e0.y, s); s = fmaf(q0.z, e0.z, s); s = fmaf(q0.w, e0.w, s);
        s = fmaf(q1.x, e1.x, s); s = fmaf(q1.y, e1.y, s); s = fmaf(q1.z, e1.z, s); s = fmaf(q1.w, e1.w, s);
        s = fmaf(q2.x, e2.x, s); s = fmaf(q2.y, e2.y, s); s = fmaf(q2.z, e2.z, s); s = fmaf(q2.w, e2.w, s);
        s = fmaf(q3.x, e3.x, s); s = fmaf(q3.y, e3.y, s); s = fmaf(q3.z, e3.z, s); s = fmaf(q3.w, e3.w, s);
        s2 = fmaf(p0.x, e0.x, s2); s2 = fmaf(p0.y, e0.y, s2); s2 = fmaf(p0.z, e0.z, s2); s2 = fmaf(p0.w, e0.w, s2);
        s2 = fmaf(p1.x, e1.x, s2); s2 = fmaf(p1.y, e1.y, s2); s2 = fmaf(p1.z, e1.z, s2); s2 = fmaf(p1.w, e1.w, s2);
        s2 = fmaf(p2.x, e2.x, s2); s2 = fmaf(p2.y, e2.y, s2); s2 = fmaf(p2.z, e2.z, s2); s2 = fmaf(p2.w, e2.w, s2);
        s2 = fmaf(p3.x, e3.x, s2); s2 = fmaf(p3.y, e3.y, s2); s2 = fmaf(p3.z, e3.z, s2); s2 = fmaf(p3.w, e3.w, s2);
        s  += __shfl_xor(s, 1, 64);  s  += __shfl_xor(s, 2, 64);
        s2 += __shfl_xor(s2, 1, 64); s2 += __shfl_xor(s2, 2, 64);
        if (part == 0) { sb[wv][j] = s; sa[wv][j] = s2; }
    }
    float sv0 = sb[wv][lane],      av0 = sa[wv][lane];
    float sv1 = sb[wv][64 + lane], av1 = sa[wv][64 + lane];

    // top-5 over 128 via two-local admissible argmax + payload
    float prevv = INFINITY; int previ = -1;
    int cI[KTOP]; float atk[KTOP];
#pragma unroll
    for (int k = 0; k < KTOP; ++k) {
        bool adm0 = (sv0 < prevv) || (sv0 == prevv && ci0 > previ);
        bool adm1 = (sv1 < prevv) || (sv1 == prevv && ci1 > previ);
        float bv = adm0 ? sv0 : -INFINITY;
        int   bi = adm0 ? ci0 : 0x7fffffff;
        float ba = av0;
        if (adm1 && (sv1 > bv || (sv1 == bv && ci1 < bi))) { bv = sv1; bi = ci1; ba = av1; }
#pragma unroll
        for (int off = 1; off < 64; off <<= 1) {
            float ov = __shfl_xor(bv, off, 64);
            int   oi = __shfl_xor(bi, off, 64);
            float oa = __shfl_xor(ba, off, 64);
            if (ov > bv || (ov == bv && oi < bi)) { bv = ov; bi = oi; ba = oa; }
        }
        cI[k] = bi; atk[k] = ba; prevv = bv; previ = bi;
    }

    float sc[KTOP];
#pragma unroll
    for (int k = 0; k < KTOP; ++k) sc[k] = atk[k] * 0.0625f;   // 1/sqrt(256)
    float mx = sc[0];
#pragma unroll
    for (int k = 1; k < KTOP; ++k) mx = fmaxf(mx, sc[k]);
    float wgt[KTOP], ssum = 0.f;
#pragma unroll
    for (int k = 0; k < KTOP; ++k) { wgt[k] = expf(sc[k] - mx); ssum += wgt[k]; }
    float inv = 1.f / ssum;

    float mm = 0.f;
#pragma unroll
    for (int k = 0; k < KTOP; ++k)
        mm = fmaf(wgt[k] * inv, ego2[(size_t)cI[k] * EDIM + lane], mm);
    smm[wv][lane] = mm;

    // out[r][d] = bv[d] + sum_e Wv[d][e]*m[e], via LDS-staged WvT in two 128-d passes
    int dl = lane * 2;
#pragma unroll
    for (int pass = 0; pass < 2; ++pass) {
        __syncthreads();   // smm visible (pass0) / previous pass reads done (pass1)
        // stage WvT[e][d] for d in [pass*128, pass*128+128): coalesced global reads
#pragma unroll
        for (int i = 0; i < 8; ++i) {
            int idx = i * 256 + t;             // 0..2047
            int d  = idx >> 4;                 // 0..127 local
            int e4 = (idx & 15) * 4;
            float4 wv4 = *(const float4*)&Wv[(size_t)(pass * 128 + d) * EDIM + e4];
            WvT[(e4 + 0) * 130 + d] = wv4.x;
            WvT[(e4 + 1) * 130 + d] = wv4.y;
            WvT[(e4 + 2) * 130 + d] = wv4.z;
            WvT[(e4 + 3) * 130 + d] = wv4.w;
        }
        __syncthreads();
        float2 acc = *(const float2*)&bv_[pass * 128 + dl];
#pragma unroll 8
        for (int e = 0; e < 64; ++e) {
            float me = smm[wv][e];             // LDS broadcast
            float2 wv2 = *(const float2*)&WvT[e * 130 + dl];
            acc.x = fmaf(me, wv2.x, acc.x);
            acc.y = fmaf(me, wv2.y, acc.y);
        }
        *(float2*)&out[(size_t)r * DQK + pass * 128 + dl] = acc;
    }
}

// ================================================================ launch
extern "C" void kernel_launch(void* const* d_in, const int* in_sizes, int n_in,
                              void* d_out, int out_size, void* d_ws, size_t ws_size,
                              hipStream_t stream) {
    const float* user  = (const float*)d_in[0];
    const float* item  = (const float*)d_in[1];
    const int*   nrows = (const int*)d_in[2];
    const int*   ncols = (const int*)d_in[3];
    const float* nvals = (const float*)d_in[4];
    const int*   arows = (const int*)d_in[5];
    const int*   acols = (const int*)d_in[6];
    const float* Wq = (const float*)d_in[8];  const float* bq = (const float*)d_in[9];
    const float* Wk = (const float*)d_in[10];
    const float* Wv = (const float*)d_in[12]; const float* bvp = (const float*)d_in[13];
    float* out = (float*)d_out;
    float* ws  = (float*)d_ws;

    const int NE = NN * EDIM;              // 393216
    float* ego1 = ws;
    float* ego2 = ws + NE;
    float* Qm   = ws + 2 * NE;
    float* P    = ws + 3 * NE;
    int*   pidx = (int*)(ws + 4 * NE);     // NN*128 ints = 2*NE
    float* Gbuf = ws + 6 * NE;             // 4160 floats
    int*   ell  = (int*)(ws + 6 * NE + 4160);
    int* cnt_n  = ell;                     // 6144
    int* cnt_a  = ell + 6144;              // 6144
    long long* cv_n = (long long*)(ell + 12288);   // NN*ELLW x 8B
    int* cv_a   = (int*)(cv_n + NN * ELLW);        // NN*ELLW x 4B

    hipMemsetAsync(cnt_n, 0, 12288 * sizeof(int), stream);
    build_kernel<<<NBUILD + 17, TPB, 0, stream>>>(nrows, ncols, nvals, arows, acols,
                                                  Wq, Wk, bq,
                                                  cnt_n, cnt_a, cv_n, cv_a, Gbuf);
    spmm_ell_emb_kernel<<<NN / 4, TPB, 0, stream>>>(cnt_n, cv_n, user, item, ego1);
    spmm_ell_kernel<<<NN / 4, TPB, 0, stream>>>(cnt_n, cv_n, ego1, ego2);
    qm_mean_kernel<<<NN / 4 + 96, TPB, 0, stream>>>(cnt_a, cv_a, ego2, ego1, user, item,
                                                    Gbuf, Qm, out, P);
    topk_kernel<<<96 * SPLITS, TPB, 0, stream>>>(ego2, Qm, pidx);
    attn_sel_kernel<<<NN / 4, TPB, 0, stream>>>(Qm, P, ego2, pidx, Wv, bvp, out + NE);
}

// Round 14
// 221.669 us; speedup vs baseline: 1.1965x; 1.0132x over previous
//
#include <hip/hip_runtime.h>
#include <hip/hip_bf16.h>
#include <math.h>

#define NUSER 2560
#define NITEM 3584
#define NN    6144
#define EDIM  64
#define NNZ   200000
#define DQK   256
#define KTOP  5
#define SPLITS 16
#define TPS    3          // 48 cand tiles / 16 splits
#define CK     8          // coarse per (row,split); 16*8=128 rescored
#define ELLW   96
#define TPB   256
#define NBUILD 1563       // ceil(2*NNZ/256)
#define BSTR  72

typedef __attribute__((ext_vector_type(8))) short bf16x8;
typedef __attribute__((ext_vector_type(4))) float f32x4;

// packed RTNE f32x2 -> bf16x2 (hardware cvt on gfx950; RTNE matches manual round-nearest-even)
__device__ __forceinline__ int pack2(float a, float b) {
    __hip_bfloat162 h = __float22bfloat162_rn(float2{a, b});
    return *(int*)&h;     // low short = a, high short = b
}
__device__ __forceinline__ void ell_unpack(long long v, int* col, float* w) {
    *col = (int)(v & 0xffffffffLL);
    *w   = __int_as_float((int)(v >> 32));
}

// ================================================================ build (COO->ELL) + G spread over 17 blocks
__global__ void build_kernel(const int* __restrict__ nr, const int* __restrict__ nc,
                             const float* __restrict__ nv,
                             const int* __restrict__ ar, const int* __restrict__ ac,
                             const float* __restrict__ Wq, const float* __restrict__ Wk,
                             const float* __restrict__ bq,
                             int* __restrict__ cnt_n, int* __restrict__ cnt_a,
                             long long* __restrict__ cv_n, int* __restrict__ cv_a,
                             float* __restrict__ Gbuf) {
    int t = threadIdx.x;

    if (blockIdx.x >= NBUILD) {
        int gb = blockIdx.x - NBUILD;
        if (gb < 16) {
            // G[e][f] = sum_d Wq[d][e]*Wk[d][f]; block gb handles e in [gb*4, gb*4+4)
            int ei = gb * 4 + (t >> 6);
            int f  = t & 63;
            float a8[8];
#pragma unroll
            for (int u = 0; u < 8; ++u) a8[u] = 0.f;
            for (int d0 = 0; d0 < DQK; d0 += 8) {
#pragma unroll
                for (int u = 0; u < 8; ++u)
                    a8[u] = fmaf(Wq[(d0 + u) * 64 + ei], Wk[(d0 + u) * 64 + f], a8[u]);
            }
            Gbuf[ei * 64 + f] = ((a8[0] + a8[1]) + (a8[2] + a8[3]))
                              + ((a8[4] + a8[5]) + (a8[6] + a8[7]));
        } else {
            // u[f] = sum_d bq[d]*Wk[d][f]
            __shared__ float sm[256];
            int f = t & 63, dq = t >> 6;
            float p = 0.f;
            for (int d = dq * 64; d < dq * 64 + 64; ++d)
                p = fmaf(bq[d], Wk[d * 64 + f], p);
            sm[t] = p;
            __syncthreads();
            if (t < 64) Gbuf[4096 + t] = ((sm[t] + sm[64 + t]) + (sm[128 + t] + sm[192 + t]));
        }
        return;
    }

    int g = blockIdx.x * TPB + t;
    if (g < NNZ) {
        int r = nr[g], c = nc[g];
        float v = nv[g];
        int slot = atomicAdd(&cnt_n[r], 1);
        long long pk = (unsigned int)c | ((long long)(unsigned int)__float_as_int(v) << 32);
        cv_n[r * ELLW + slot] = pk;
    } else if (g < 2 * NNZ) {
        int h = g - NNZ;
        int r = ar[h], c = ac[h];
        int slot = atomicAdd(&cnt_a[r], 1);
        cv_a[r * ELLW + slot] = c;
    }
}

// ================================================================ ELL SpMM, wave-per-row, x8 unroll
__global__ __launch_bounds__(TPB) void spmm_ell_emb_kernel(
        const int* __restrict__ cnt, const long long* __restrict__ cv,
        const float* __restrict__ user, const float* __restrict__ item,
        float* __restrict__ dst) {
    int r = blockIdx.x * 4 + (threadIdx.x >> 6);
    int lane = threadIdx.x & 63;
    int s = r * ELLW, e = s + cnt[r];
    float a[8];
#pragma unroll
    for (int u = 0; u < 8; ++u) a[u] = 0.f;
    int j = s, n8 = s + ((e - s) & ~7);
    for (; j < n8; j += 8) {
        int col[8]; float w[8];
#pragma unroll
        for (int u = 0; u < 8; ++u) ell_unpack(cv[j + u], &col[u], &w[u]);
#pragma unroll
        for (int u = 0; u < 8; ++u) {
            float x = (col[u] < NUSER) ? user[col[u] * EDIM + lane]
                                       : item[(col[u] - NUSER) * EDIM + lane];
            a[u] = fmaf(w[u], x, a[u]);
        }
    }
    for (; j < e; ++j) {
        int col; float w;
        ell_unpack(cv[j], &col, &w);
        float x = (col < NUSER) ? user[col * EDIM + lane] : item[(col - NUSER) * EDIM + lane];
        a[0] = fmaf(w, x, a[0]);
    }
    dst[r * EDIM + lane] = ((a[0] + a[1]) + (a[2] + a[3])) + ((a[4] + a[5]) + (a[6] + a[7]));
}

__global__ __launch_bounds__(TPB) void spmm_ell_kernel(
        const int* __restrict__ cnt, const long long* __restrict__ cv,
        const float* __restrict__ src, float* __restrict__ dst) {
    int r = blockIdx.x * 4 + (threadIdx.x >> 6);
    int lane = threadIdx.x & 63;
    int s = r * ELLW, e = s + cnt[r];
    float a[8];
#pragma unroll
    for (int u = 0; u < 8; ++u) a[u] = 0.f;
    int j = s, n8 = s + ((e - s) & ~7);
    for (; j < n8; j += 8) {
        int col[8]; float w[8];
#pragma unroll
        for (int u = 0; u < 8; ++u) ell_unpack(cv[j + u], &col[u], &w[u]);
#pragma unroll
        for (int u = 0; u < 8; ++u)
            a[u] = fmaf(w[u], src[col[u] * EDIM + lane], a[u]);
    }
    for (; j < e; ++j) {
        int col; float w;
        ell_unpack(cv[j], &col, &w);
        a[0] = fmaf(w, src[col * EDIM + lane], a[0]);
    }
    dst[r * EDIM + lane] = ((a[0] + a[1]) + (a[2] + a[3])) + ((a[4] + a[5]) + (a[6] + a[7]));
}

// Qm = ego2 + 0.5*(A@ego2) ; outmean = 0.5*(ego0+ego1)
__global__ __launch_bounds__(TPB) void qm_mean_kernel(
        const int* __restrict__ cnt, const int* __restrict__ cv,
        const float* __restrict__ ego2, const float* __restrict__ ego1,
        const float* __restrict__ user, const float* __restrict__ item,
        float* __restrict__ Qm, float* __restrict__ outmean) {
    int t = threadIdx.x;
    int r = blockIdx.x * 4 + (t >> 6);
    int lane = t & 63;
    int s = r * ELLW, e = s + cnt[r];
    float a[8];
#pragma unroll
    for (int u = 0; u < 8; ++u) a[u] = 0.f;
    int j = s, n8 = s + ((e - s) & ~7);
    for (; j < n8; j += 8) {
        int col[8];
#pragma unroll
        for (int u = 0; u < 8; ++u) col[u] = cv[j + u];
#pragma unroll
        for (int u = 0; u < 8; ++u)
            a[u] += ego2[col[u] * EDIM + lane];
    }
    for (; j < e; ++j) a[0] += ego2[cv[j] * EDIM + lane];
    float acc = ((a[0] + a[1]) + (a[2] + a[3])) + ((a[4] + a[5]) + (a[6] + a[7]));
    int o = r * EDIM + lane;
    Qm[o] = ego2[o] + 0.5f * acc;
    float e0v = (r < NUSER) ? user[o] : item[o - NUSER * EDIM];
    outmean[o] = 0.5f * (e0v + ego1[o]);
}

// ================================================================ MFMA coarse top-8 (1536 blocks, 6 blk/CU)
__device__ __forceinline__ void ins3(float v, int ci, float tv[3], int ti[3]) {
    if (v > tv[2]) {
        bool p1 = v > tv[1], p0 = v > tv[0];
        tv[2] = p1 ? tv[1] : v;  ti[2] = p1 ? ti[1] : ci;
        if (p1) { tv[1] = p0 ? tv[0] : v; ti[1] = p0 ? ti[0] : ci; }
        if (p0) { tv[0] = v; ti[0] = ci; }
    }
}

__global__ __launch_bounds__(TPB, 6) void topk_kernel(
        const float* __restrict__ ego2, const float* __restrict__ Qm,
        int* __restrict__ pidx) {
    __shared__ __align__(16) short smem[13312];   // Ah 4096 + Bh 9216 shorts = 26.6 KB
    int t = threadIdx.x;
    int rb = blockIdx.x % 96, sp = blockIdx.x / 96;
    int r0 = rb * 64;
    int w = t >> 6, lane = t & 63, lq = lane >> 4, lc = lane & 15;

    short* Ah = smem;            // [64][64] bf16 row-major
    short* Bh = smem + 4096;     // [128][BSTR=72] bf16 padded

    { // stage A from fp32 Qm (once per block)
        int row = t >> 2, seg = t & 3;
        const float4* src = (const float4*)&Qm[(size_t)(r0 + row) * EDIM + seg * 16];
        float4 f0 = src[0], f1 = src[1], f2 = src[2], f3 = src[3];
        int4 p0, p1;
        p0.x = pack2(f0.x, f0.y); p0.y = pack2(f0.z, f0.w);
        p0.z = pack2(f1.x, f1.y); p0.w = pack2(f1.z, f1.w);
        p1.x = pack2(f2.x, f2.y); p1.y = pack2(f2.z, f2.w);
        p1.z = pack2(f3.x, f3.y); p1.w = pack2(f3.z, f3.w);
        *(int4*)&Ah[row * EDIM + seg * 16] = p0;
        *(int4*)&Ah[row * EDIM + seg * 16 + 8] = p1;
    }

    float4 pa[4], pb[4];
    { // prefetch tile 0 (fp32)
        int c0 = (sp * TPS) * 128;
#pragma unroll
        for (int rep = 0; rep < 4; ++rep) {
            int v = t + 256 * rep;
            const float4* src = (const float4*)&ego2[(size_t)(c0 + (v >> 3)) * EDIM + (v & 7) * 8];
            pa[rep] = src[0]; pb[rep] = src[1];
        }
    }

    float t3v[4][3]; int t3i[4][3];
#pragma unroll
    for (int i = 0; i < 4; ++i)
#pragma unroll
        for (int k = 0; k < 3; ++k) { t3v[i][k] = -INFINITY; t3i[i][k] = 0x7fffffff; }

    bf16x8 af0, af1;
    for (int tile = 0; tile < TPS; ++tile) {
        int c0 = (sp * TPS + tile) * 128;
        __syncthreads();
        {
#pragma unroll
            for (int rep = 0; rep < 4; ++rep) {
                int v = t + 256 * rep;
                int4 q;
                q.x = pack2(pa[rep].x, pa[rep].y); q.y = pack2(pa[rep].z, pa[rep].w);
                q.z = pack2(pb[rep].x, pb[rep].y); q.w = pack2(pb[rep].z, pb[rep].w);
                *(int4*)&Bh[(v >> 3) * BSTR + (v & 7) * 8] = q;
            }
        }
        if (tile + 1 < TPS) {
            int c1 = c0 + 128;
#pragma unroll
            for (int rep = 0; rep < 4; ++rep) {
                int v = t + 256 * rep;
                const float4* src = (const float4*)&ego2[(size_t)(c1 + (v >> 3)) * EDIM + (v & 7) * 8];
                pa[rep] = src[0]; pb[rep] = src[1];
            }
        }
        __syncthreads();
        if (tile == 0) {
            af0 = *(const bf16x8*)&Ah[(w * 16 + lc) * EDIM + lq * 8];
            af1 = *(const bf16x8*)&Ah[(w * 16 + lc) * EDIM + 32 + lq * 8];
        }

#pragma unroll
        for (int ch = 0; ch < 8; ++ch) {
            bf16x8 b0 = *(const bf16x8*)&Bh[(ch * 16 + lc) * BSTR + lq * 8];
            bf16x8 b1 = *(const bf16x8*)&Bh[(ch * 16 + lc) * BSTR + 32 + lq * 8];
            f32x4 acc = {0.f, 0.f, 0.f, 0.f};
            acc = __builtin_amdgcn_mfma_f32_16x16x32_bf16(af0, b0, acc, 0, 0, 0);
            acc = __builtin_amdgcn_mfma_f32_16x16x32_bf16(af1, b1, acc, 0, 0, 0);
            int ci = c0 + ch * 16 + lc;
#pragma unroll
            for (int reg = 0; reg < 4; ++reg)
                ins3(acc[reg], ci, t3v[reg], t3i[reg]);
        }
    }

    // merge: shift-head sequential argmax over 16 lanes' sorted top-3 lists (exact; (v,idx) unique)
#pragma unroll
    for (int i = 0; i < 4; ++i) {
        int row = r0 + w * 16 + lq * 4 + i;
        float h0 = t3v[i][0], h1 = t3v[i][1], h2 = t3v[i][2];
        int   j0 = t3i[i][0], j1 = t3i[i][1], j2 = t3i[i][2];
        for (int k = 0; k < CK; ++k) {
            float bv = h0; int bi = j0;
#pragma unroll
            for (int off = 1; off < 16; off <<= 1) {
                float ov = __shfl_xor(bv, off, 64);
                int   oi = __shfl_xor(bi, off, 64);
                if (ov > bv || (ov == bv && oi < bi)) { bv = ov; bi = oi; }
            }
            bool cons = (bv == h0 && bi == j0);
            if (cons) { h0 = h1; j0 = j1; h1 = h2; j1 = j2; h2 = -INFINITY; j2 = 0x7fffffff; }
            if (lc == 0) pidx[(row * SPLITS + sp) * CK + k] = bi;
        }
    }
}

// ================================================================ rescore(128) + top-5 + softmax + WvT-staged out
// P-row computed in-kernel from G (same fma order as the old P kernel -> bitwise identical)
__global__ __launch_bounds__(TPB) void attn_sel_kernel(
        const float* __restrict__ Qm, const float* __restrict__ ego2,
        const int* __restrict__ pidx, const float* __restrict__ Gbuf,
        const float* __restrict__ Wv, const float* __restrict__ bv_,
        float* __restrict__ out) {
    __shared__ float sb[4][128];
    __shared__ float sa[4][128];
    __shared__ float smm[4][64];
    __shared__ float sqp[4][64];
    __shared__ float stage[64 * 130];   // phase 1: G (4160 floats); phase 2: WvT
    int wv = threadIdx.x >> 6, lane = threadIdx.x & 63;
    int t = threadIdx.x;
    int r = blockIdx.x * 4 + wv;
    int ci0 = pidx[r * 128 + lane];
    int ci1 = pidx[r * 128 + 64 + lane];
    int part = lane & 3;

    { // stage G + u
#pragma unroll
        for (int i = 0; i < 17; ++i) {
            int v = i * 256 + t;
            if (v < 4160) stage[v] = Gbuf[v];
        }
    }
    __syncthreads();

    // P[r][lane] = u[lane] + sum_e ego2[r][e]*G[e][lane]  (e ascending, fma chain)
    {
        float qv = ego2[(size_t)r * EDIM + lane];
        float pr = stage[4096 + lane];
#pragma unroll 8
        for (int e = 0; e < 64; ++e)
            pr = fmaf(__shfl(qv, e, 64), stage[e * 64 + lane], pr);
        sqp[wv][lane] = pr;
    }

    const float4* qmp = (const float4*)(Qm + (size_t)r * EDIM + part * 16);
    float4 q0 = qmp[0], q1 = qmp[1], q2 = qmp[2], q3 = qmp[3];
    const float4* pmp = (const float4*)&sqp[wv][part * 16];
    float4 p0 = pmp[0], p1 = pmp[1], p2 = pmp[2], p3 = pmp[3];

    // rescore 128 cands: quad-per-cand, coalesced 4-lane row reads, quad shuffle-reduce
#pragma unroll
    for (int p = 0; p < 8; ++p) {
        int j = p * 16 + (lane >> 2);                 // 0..127
        int c = (j < 64) ? __shfl(ci0, j, 64) : __shfl(ci1, j - 64, 64);
        const float4* ep = (const float4*)(ego2 + (size_t)c * EDIM + part * 16);
        float4 e0 = ep[0], e1 = ep[1], e2 = ep[2], e3 = ep[3];
        float s = 0.f, s2 = 0.f;
        s = fmaf(q0.x, e0.x, s); s = fmaf(q0.y, e0.y, s); s = fmaf(q0.z, e0.z, s); s = fmaf(q0.w, e0.w, s);
        s = fmaf(q1.x, e1.x, s); s = fmaf(q1.y, e1.y, s); s = fmaf(q1.z, e1.z, s); s = fmaf(q1.w, e1.w, s);
        s = fmaf(q2.x, e2.x, s); s = fmaf(q2.y, e2.y, s); s = fmaf(q2.z, e2.z, s); s = fmaf(q2.w, e2.w, s);
        s = fmaf(q3.x, e3.x, s); s = fmaf(q3.y, e3.y, s); s = fmaf(q3.z, e3.z, s); s = fmaf(q3.w, e3.w, s);
        s2 = fmaf(p0.x, e0.x, s2); s2 = fmaf(p0.y, e0.y, s2); s2 = fmaf(p0.z, e0.z, s2); s2 = fmaf(p0.w, e0.w, s2);
        s2 = fmaf(p1.x, e1.x, s2); s2 = fmaf(p1.y, e1.y, s2); s2 = fmaf(p1.z, e1.z, s2); s2 = fmaf(p1.w, e1.w, s2);
        s2 = fmaf(p2.x, e2.x, s2); s2 = fmaf(p2.y, e2.y, s2); s2 = fmaf(p2.z, e2.z, s2); s2 = fmaf(p2.w, e2.w, s2);
        s2 = fmaf(p3.x, e3.x, s2); s2 = fmaf(p3.y, e3.y, s2); s2 = fmaf(p3.z, e3.z, s2); s2 = fmaf(p3.w, e3.w, s2);
        s  += __shfl_xor(s, 1, 64);  s  += __shfl_xor(s, 2, 64);
        s2 += __shfl_xor(s2, 1, 64); s2 += __shfl_xor(s2, 2, 64);
        if (part == 0) { sb[wv][j] = s; sa[wv][j] = s2; }
    }
    float sv0 = sb[wv][lane],      av0 = sa[wv][lane];
    float sv1 = sb[wv][64 + lane], av1 = sa[wv][64 + lane];

    // top-5 over 128 via two-local admissible argmax + payload
    float prevv = INFINITY; int previ = -1;
    int cI[KTOP]; float atk[KTOP];
#pragma unroll
    for (int k = 0; k < KTOP; ++k) {
        bool adm0 = (sv0 < prevv) || (sv0 == prevv && ci0 > previ);
        bool adm1 = (sv1 < prevv) || (sv1 == prevv && ci1 > previ);
        float bv = adm0 ? sv0 : -INFINITY;
        int   bi = adm0 ? ci0 : 0x7fffffff;
        float ba = av0;
        if (adm1 && (sv1 > bv || (sv1 == bv && ci1 < bi))) { bv = sv1; bi = ci1; ba = av1; }
#pragma unroll
        for (int off = 1; off < 64; off <<= 1) {
            float ov = __shfl_xor(bv, off, 64);
            int   oi = __shfl_xor(bi, off, 64);
            float oa = __shfl_xor(ba, off, 64);
            if (ov > bv || (ov == bv && oi < bi)) { bv = ov; bi = oi; ba = oa; }
        }
        cI[k] = bi; atk[k] = ba; prevv = bv; previ = bi;
    }

    float sc[KTOP];
#pragma unroll
    for (int k = 0; k < KTOP; ++k) sc[k] = atk[k] * 0.0625f;   // 1/sqrt(256)
    float mx = sc[0];
#pragma unroll
    for (int k = 1; k < KTOP; ++k) mx = fmaxf(mx, sc[k]);
    float wgt[KTOP], ssum = 0.f;
#pragma unroll
    for (int k = 0; k < KTOP; ++k) { wgt[k] = expf(sc[k] - mx); ssum += wgt[k]; }
    float inv = 1.f / ssum;

    float mm = 0.f;
#pragma unroll
    for (int k = 0; k < KTOP; ++k)
        mm = fmaf(wgt[k] * inv, ego2[(size_t)cI[k] * EDIM + lane], mm);
    smm[wv][lane] = mm;

    // out[r][d] = bv[d] + sum_e Wv[d][e]*m[e], via LDS-staged WvT in two 128-d passes
    int dl = lane * 2;
#pragma unroll
    for (int pass = 0; pass < 2; ++pass) {
        __syncthreads();   // smm visible & G reads done (pass0) / previous pass reads done (pass1)
#pragma unroll
        for (int i = 0; i < 8; ++i) {
            int idx = i * 256 + t;             // 0..2047
            int d  = idx >> 4;                 // 0..127 local
            int e4 = (idx & 15) * 4;
            float4 wv4 = *(const float4*)&Wv[(size_t)(pass * 128 + d) * EDIM + e4];
            stage[(e4 + 0) * 130 + d] = wv4.x;
            stage[(e4 + 1) * 130 + d] = wv4.y;
            stage[(e4 + 2) * 130 + d] = wv4.z;
            stage[(e4 + 3) * 130 + d] = wv4.w;
        }
        __syncthreads();
        float2 acc = *(const float2*)&bv_[pass * 128 + dl];
#pragma unroll 8
        for (int e = 0; e < 64; ++e) {
            float me = smm[wv][e];             // LDS broadcast
            float2 wv2 = *(const float2*)&stage[e * 130 + dl];
            acc.x = fmaf(me, wv2.x, acc.x);
            acc.y = fmaf(me, wv2.y, acc.y);
        }
        *(float2*)&out[(size_t)r * DQK + pass * 128 + dl] = acc;
    }
}

// ================================================================ launch
extern "C" void kernel_launch(void* const* d_in, const int* in_sizes, int n_in,
                              void* d_out, int out_size, void* d_ws, size_t ws_size,
                              hipStream_t stream) {
    const float* user  = (const float*)d_in[0];
    const float* item  = (const float*)d_in[1];
    const int*   nrows = (const int*)d_in[2];
    const int*   ncols = (const int*)d_in[3];
    const float* nvals = (const float*)d_in[4];
    const int*   arows = (const int*)d_in[5];
    const int*   acols = (const int*)d_in[6];
    const float* Wq = (const float*)d_in[8];  const float* bq = (const float*)d_in[9];
    const float* Wk = (const float*)d_in[10];
    const float* Wv = (const float*)d_in[12]; const float* bvp = (const float*)d_in[13];
    float* out = (float*)d_out;
    float* ws  = (float*)d_ws;

    const int NE = NN * EDIM;              // 393216
    float* ego1 = ws;
    float* ego2 = ws + NE;
    float* Qm   = ws + 2 * NE;
    int*   pidx = (int*)(ws + 3 * NE);     // NN*128 ints = 2*NE
    float* Gbuf = ws + 5 * NE;             // 4160 floats
    int*   ell  = (int*)(ws + 5 * NE + 4160);
    int* cnt_n  = ell;                     // 6144
    int* cnt_a  = ell + 6144;              // 6144
    long long* cv_n = (long long*)(ell + 12288);   // NN*ELLW x 8B
    int* cv_a   = (int*)(cv_n + NN * ELLW);        // NN*ELLW x 4B

    hipMemsetAsync(cnt_n, 0, 12288 * sizeof(int), stream);
    build_kernel<<<NBUILD + 17, TPB, 0, stream>>>(nrows, ncols, nvals, arows, acols,
                                                  Wq, Wk, bq,
                                                  cnt_n, cnt_a, cv_n, cv_a, Gbuf);
    spmm_ell_emb_kernel<<<NN / 4, TPB, 0, stream>>>(cnt_n, cv_n, user, item, ego1);
    spmm_ell_kernel<<<NN / 4, TPB, 0, stream>>>(cnt_n, cv_n, ego1, ego2);
    qm_mean_kernel<<<NN / 4, TPB, 0, stream>>>(cnt_a, cv_a, ego2, ego1, user, item, Qm, out);
    topk_kernel<<<96 * SPLITS, TPB, 0, stream>>>(ego2, Qm, pidx);
    attn_sel_kernel<<<NN / 4, TPB, 0, stream>>>(Qm, ego2, pidx, Gbuf, Wv, bvp, out + NE);
}

// Round 15
// 210.639 us; speedup vs baseline: 1.2592x; 1.0524x over previous
//
#include <hip/hip_runtime.h>
#include <hip/hip_bf16.h>
#include <math.h>

#define NUSER 2560
#define NITEM 3584
#define NN    6144
#define EDIM  64
#define NNZ   200000
#define DQK   256
#define KTOP  5
#define SPLITS 16
#define TPS    3          // 48 cand tiles / 16 splits
#define CK     8          // coarse per (row,split); 16*8=128 rescored
#define ELLW   96
#define TPB   256
#define NBUILD 1563       // ceil(2*NNZ/256)
#define BSTR  72

typedef __attribute__((ext_vector_type(8))) short bf16x8;
typedef __attribute__((ext_vector_type(4))) float f32x4;

// packed RTNE f32x2 -> bf16x2 (hardware cvt; matches manual round-nearest-even)
__device__ __forceinline__ int pack2(float a, float b) {
    __hip_bfloat162 h = __float22bfloat162_rn(float2{a, b});
    return *(int*)&h;
}
__device__ __forceinline__ void ell_unpack(long long v, int* col, float* w) {
    *col = (int)(v & 0xffffffffLL);
    *w   = __int_as_float((int)(v >> 32));
}

// ================================================================ build (COO->ELL) + G spread over 17 blocks
__global__ void build_kernel(const int* __restrict__ nr, const int* __restrict__ nc,
                             const float* __restrict__ nv,
                             const int* __restrict__ ar, const int* __restrict__ ac,
                             const float* __restrict__ Wq, const float* __restrict__ Wk,
                             const float* __restrict__ bq,
                             int* __restrict__ cnt_n, int* __restrict__ cnt_a,
                             long long* __restrict__ cv_n, int* __restrict__ cv_a,
                             float* __restrict__ Gbuf) {
    int t = threadIdx.x;

    if (blockIdx.x >= NBUILD) {
        int gb = blockIdx.x - NBUILD;
        if (gb < 16) {
            int ei = gb * 4 + (t >> 6);
            int f  = t & 63;
            float a8[8];
#pragma unroll
            for (int u = 0; u < 8; ++u) a8[u] = 0.f;
            for (int d0 = 0; d0 < DQK; d0 += 8) {
#pragma unroll
                for (int u = 0; u < 8; ++u)
                    a8[u] = fmaf(Wq[(d0 + u) * 64 + ei], Wk[(d0 + u) * 64 + f], a8[u]);
            }
            Gbuf[ei * 64 + f] = ((a8[0] + a8[1]) + (a8[2] + a8[3]))
                              + ((a8[4] + a8[5]) + (a8[6] + a8[7]));
        } else {
            __shared__ float sm[256];
            int f = t & 63, dq = t >> 6;
            float p = 0.f;
            for (int d = dq * 64; d < dq * 64 + 64; ++d)
                p = fmaf(bq[d], Wk[d * 64 + f], p);
            sm[t] = p;
            __syncthreads();
            if (t < 64) Gbuf[4096 + t] = ((sm[t] + sm[64 + t]) + (sm[128 + t] + sm[192 + t]));
        }
        return;
    }

    int g = blockIdx.x * TPB + t;
    if (g < NNZ) {
        int r = nr[g], c = nc[g];
        float v = nv[g];
        int slot = atomicAdd(&cnt_n[r], 1);
        long long pk = (unsigned int)c | ((long long)(unsigned int)__float_as_int(v) << 32);
        cv_n[r * ELLW + slot] = pk;
    } else if (g < 2 * NNZ) {
        int h = g - NNZ;
        int r = ar[h], c = ac[h];
        int slot = atomicAdd(&cnt_a[r], 1);
        cv_a[r * ELLW + slot] = c;
    }
}

// ================================================================ ELL SpMM, wave-per-row, x8 unroll
__global__ __launch_bounds__(TPB) void spmm_ell_emb_kernel(
        const int* __restrict__ cnt, const long long* __restrict__ cv,
        const float* __restrict__ user, const float* __restrict__ item,
        float* __restrict__ dst) {
    int r = blockIdx.x * 4 + (threadIdx.x >> 6);
    int lane = threadIdx.x & 63;
    int s = r * ELLW, e = s + cnt[r];
    float a[8];
#pragma unroll
    for (int u = 0; u < 8; ++u) a[u] = 0.f;
    int j = s, n8 = s + ((e - s) & ~7);
    for (; j < n8; j += 8) {
        int col[8]; float w[8];
#pragma unroll
        for (int u = 0; u < 8; ++u) ell_unpack(cv[j + u], &col[u], &w[u]);
#pragma unroll
        for (int u = 0; u < 8; ++u) {
            float x = (col[u] < NUSER) ? user[col[u] * EDIM + lane]
                                       : item[(col[u] - NUSER) * EDIM + lane];
            a[u] = fmaf(w[u], x, a[u]);
        }
    }
    for (; j < e; ++j) {
        int col; float w;
        ell_unpack(cv[j], &col, &w);
        float x = (col < NUSER) ? user[col * EDIM + lane] : item[(col - NUSER) * EDIM + lane];
        a[0] = fmaf(w, x, a[0]);
    }
    dst[r * EDIM + lane] = ((a[0] + a[1]) + (a[2] + a[3])) + ((a[4] + a[5]) + (a[6] + a[7]));
}

__global__ __launch_bounds__(TPB) void spmm_ell_kernel(
        const int* __restrict__ cnt, const long long* __restrict__ cv,
        const float* __restrict__ src, float* __restrict__ dst) {
    int r = blockIdx.x * 4 + (threadIdx.x >> 6);
    int lane = threadIdx.x & 63;
    int s = r * ELLW, e = s + cnt[r];
    float a[8];
#pragma unroll
    for (int u = 0; u < 8; ++u) a[u] = 0.f;
    int j = s, n8 = s + ((e - s) & ~7);
    for (; j < n8; j += 8) {
        int col[8]; float w[8];
#pragma unroll
        for (int u = 0; u < 8; ++u) ell_unpack(cv[j + u], &col[u], &w[u]);
#pragma unroll
        for (int u = 0; u < 8; ++u)
            a[u] = fmaf(w[u], src[col[u] * EDIM + lane], a[u]);
    }
    for (; j < e; ++j) {
        int col; float w;
        ell_unpack(cv[j], &col, &w);
        a[0] = fmaf(w, src[col * EDIM + lane], a[0]);
    }
    dst[r * EDIM + lane] = ((a[0] + a[1]) + (a[2] + a[3])) + ((a[4] + a[5]) + (a[6] + a[7]));
}

// Qm = ego2 + 0.5*(A@ego2) ; outmean = 0.5*(ego0+ego1)
__global__ __launch_bounds__(TPB) void qm_mean_kernel(
        const int* __restrict__ cnt, const int* __restrict__ cv,
        const float* __restrict__ ego2, const float* __restrict__ ego1,
        const float* __restrict__ user, const float* __restrict__ item,
        float* __restrict__ Qm, float* __restrict__ outmean) {
    int t = threadIdx.x;
    int r = blockIdx.x * 4 + (t >> 6);
    int lane = t & 63;
    int s = r * ELLW, e = s + cnt[r];
    float a[8];
#pragma unroll
    for (int u = 0; u < 8; ++u) a[u] = 0.f;
    int j = s, n8 = s + ((e - s) & ~7);
    for (; j < n8; j += 8) {
        int col[8];
#pragma unroll
        for (int u = 0; u < 8; ++u) col[u] = cv[j + u];
#pragma unroll
        for (int u = 0; u < 8; ++u)
            a[u] += ego2[col[u] * EDIM + lane];
    }
    for (; j < e; ++j) a[0] += ego2[cv[j] * EDIM + lane];
    float acc = ((a[0] + a[1]) + (a[2] + a[3])) + ((a[4] + a[5]) + (a[6] + a[7]));
    int o = r * EDIM + lane;
    Qm[o] = ego2[o] + 0.5f * acc;
    float e0v = (r < NUSER) ? user[o] : item[o - NUSER * EDIM];
    outmean[o] = 0.5f * (e0v + ego1[o]);
}

// ================================================================ MFMA coarse top-8 (1536 blocks, 6 blk/CU)
__device__ __forceinline__ void ins3(float v, int ci, float tv[3], int ti[3]) {
    if (v > tv[2]) {
        bool p1 = v > tv[1], p0 = v > tv[0];
        tv[2] = p1 ? tv[1] : v;  ti[2] = p1 ? ti[1] : ci;
        if (p1) { tv[1] = p0 ? tv[0] : v; ti[1] = p0 ? ti[0] : ci; }
        if (p0) { tv[0] = v; ti[0] = ci; }
    }
}

__global__ __launch_bounds__(TPB, 6) void topk_kernel(
        const float* __restrict__ ego2, const float* __restrict__ Qm,
        int* __restrict__ pidx) {
    __shared__ __align__(16) short smem[13312];   // Ah 4096 + Bh 9216 shorts = 26.6 KB
    int t = threadIdx.x;
    int rb = blockIdx.x % 96, sp = blockIdx.x / 96;
    int r0 = rb * 64;
    int w = t >> 6, lane = t & 63, lq = lane >> 4, lc = lane & 15;

    short* Ah = smem;            // [64][64] bf16 row-major
    short* Bh = smem + 4096;     // [128][BSTR=72] bf16 padded

    { // stage A from fp32 Qm (once per block)
        int row = t >> 2, seg = t & 3;
        const float4* src = (const float4*)&Qm[(size_t)(r0 + row) * EDIM + seg * 16];
        float4 f0 = src[0], f1 = src[1], f2 = src[2], f3 = src[3];
        int4 p0, p1;
        p0.x = pack2(f0.x, f0.y); p0.y = pack2(f0.z, f0.w);
        p0.z = pack2(f1.x, f1.y); p0.w = pack2(f1.z, f1.w);
        p1.x = pack2(f2.x, f2.y); p1.y = pack2(f2.z, f2.w);
        p1.z = pack2(f3.x, f3.y); p1.w = pack2(f3.z, f3.w);
        *(int4*)&Ah[row * EDIM + seg * 16] = p0;
        *(int4*)&Ah[row * EDIM + seg * 16 + 8] = p1;
    }

    float4 pa[4], pb[4];
    { // prefetch tile 0 (fp32)
        int c0 = (sp * TPS) * 128;
#pragma unroll
        for (int rep = 0; rep < 4; ++rep) {
            int v = t + 256 * rep;
            const float4* src = (const float4*)&ego2[(size_t)(c0 + (v >> 3)) * EDIM + (v & 7) * 8];
            pa[rep] = src[0]; pb[rep] = src[1];
        }
    }

    float t3v[4][3]; int t3i[4][3];
#pragma unroll
    for (int i = 0; i < 4; ++i)
#pragma unroll
        for (int k = 0; k < 3; ++k) { t3v[i][k] = -INFINITY; t3i[i][k] = 0x7fffffff; }

    bf16x8 af0, af1;
    for (int tile = 0; tile < TPS; ++tile) {
        int c0 = (sp * TPS + tile) * 128;
        __syncthreads();
        {
#pragma unroll
            for (int rep = 0; rep < 4; ++rep) {
                int v = t + 256 * rep;
                int4 q;
                q.x = pack2(pa[rep].x, pa[rep].y); q.y = pack2(pa[rep].z, pa[rep].w);
                q.z = pack2(pb[rep].x, pb[rep].y); q.w = pack2(pb[rep].z, pb[rep].w);
                *(int4*)&Bh[(v >> 3) * BSTR + (v & 7) * 8] = q;
            }
        }
        if (tile + 1 < TPS) {
            int c1 = c0 + 128;
#pragma unroll
            for (int rep = 0; rep < 4; ++rep) {
                int v = t + 256 * rep;
                const float4* src = (const float4*)&ego2[(size_t)(c1 + (v >> 3)) * EDIM + (v & 7) * 8];
                pa[rep] = src[0]; pb[rep] = src[1];
            }
        }
        __syncthreads();
        if (tile == 0) {
            af0 = *(const bf16x8*)&Ah[(w * 16 + lc) * EDIM + lq * 8];
            af1 = *(const bf16x8*)&Ah[(w * 16 + lc) * EDIM + 32 + lq * 8];
        }

#pragma unroll
        for (int ch = 0; ch < 8; ++ch) {
            bf16x8 b0 = *(const bf16x8*)&Bh[(ch * 16 + lc) * BSTR + lq * 8];
            bf16x8 b1 = *(const bf16x8*)&Bh[(ch * 16 + lc) * BSTR + 32 + lq * 8];
            f32x4 acc = {0.f, 0.f, 0.f, 0.f};
            acc = __builtin_amdgcn_mfma_f32_16x16x32_bf16(af0, b0, acc, 0, 0, 0);
            acc = __builtin_amdgcn_mfma_f32_16x16x32_bf16(af1, b1, acc, 0, 0, 0);
            int ci = c0 + ch * 16 + lc;
#pragma unroll
            for (int reg = 0; reg < 4; ++reg)
                ins3(acc[reg], ci, t3v[reg], t3i[reg]);
        }
    }

    // merge: shift-head sequential argmax over 16 lanes' sorted top-3 lists (exact; (v,idx) unique)
#pragma unroll
    for (int i = 0; i < 4; ++i) {
        int row = r0 + w * 16 + lq * 4 + i;
        float h0 = t3v[i][0], h1 = t3v[i][1], h2 = t3v[i][2];
        int   j0 = t3i[i][0], j1 = t3i[i][1], j2 = t3i[i][2];
        for (int k = 0; k < CK; ++k) {
            float bv = h0; int bi = j0;
#pragma unroll
            for (int off = 1; off < 16; off <<= 1) {
                float ov = __shfl_xor(bv, off, 64);
                int   oi = __shfl_xor(bi, off, 64);
                if (ov > bv || (ov == bv && oi < bi)) { bv = ov; bi = oi; }
            }
            bool cons = (bv == h0 && bi == j0);
            if (cons) { h0 = h1; j0 = j1; h1 = h2; j1 = j2; h2 = -INFINITY; j2 = 0x7fffffff; }
            if (lc == 0) pidx[(row * SPLITS + sp) * CK + k] = bi;
        }
    }
}

// ================================================================ rescore(128) + top-5 + softmax -> m
// P-row computed in-kernel from G (same fma order as dedicated P kernel -> bitwise identical)
__global__ __launch_bounds__(TPB) void attn_sel_kernel(
        const float* __restrict__ Qm, const float* __restrict__ ego2,
        const int* __restrict__ pidx, const float* __restrict__ Gbuf,
        float* __restrict__ m) {
    __shared__ float sb[4][128];
    __shared__ float sa[4][128];
    __shared__ float sqp[4][64];
    __shared__ float Gs[4160];
    int wv = threadIdx.x >> 6, lane = threadIdx.x & 63;
    int t = threadIdx.x;
    int r = blockIdx.x * 4 + wv;
    int ci0 = pidx[r * 128 + lane];
    int ci1 = pidx[r * 128 + 64 + lane];
    int part = lane & 3;

    { // stage G + u
#pragma unroll
        for (int i = 0; i < 17; ++i) {
            int v = i * 256 + t;
            if (v < 4160) Gs[v] = Gbuf[v];
        }
    }
    __syncthreads();

    // P[r][lane] = u[lane] + sum_e ego2[r][e]*G[e][lane]
    {
        float qv = ego2[(size_t)r * EDIM + lane];
        float pr = Gs[4096 + lane];
#pragma unroll 8
        for (int e = 0; e < 64; ++e)
            pr = fmaf(__shfl(qv, e, 64), Gs[e * 64 + lane], pr);
        sqp[wv][lane] = pr;
    }

    const float4* qmp = (const float4*)(Qm + (size_t)r * EDIM + part * 16);
    float4 q0 = qmp[0], q1 = qmp[1], q2 = qmp[2], q3 = qmp[3];
    const float4* pmp = (const float4*)&sqp[wv][part * 16];
    float4 p0 = pmp[0], p1 = pmp[1], p2 = pmp[2], p3 = pmp[3];

    // rescore 128 cands: quad-per-cand, coalesced 4-lane row reads, quad shuffle-reduce
#pragma unroll
    for (int p = 0; p < 8; ++p) {
        int j = p * 16 + (lane >> 2);                 // 0..127
        int c = (j < 64) ? __shfl(ci0, j, 64) : __shfl(ci1, j - 64, 64);
        const float4* ep = (const float4*)(ego2 + (size_t)c * EDIM + part * 16);
        float4 e0 = ep[0], e1 = ep[1], e2 = ep[2], e3 = ep[3];
        float s = 0.f, s2 = 0.f;
        s = fmaf(q0.x, e0.x, s); s = fmaf(q0.y, e0.y, s); s = fmaf(q0.z, e0.z, s); s = fmaf(q0.w, e0.w, s);
        s = fmaf(q1.x, e1.x, s); s = fmaf(q1.y, e1.y, s); s = fmaf(q1.z, e1.z, s); s = fmaf(q1.w, e1.w, s);
        s = fmaf(q2.x, e2.x, s); s = fmaf(q2.y, e2.y, s); s = fmaf(q2.z, e2.z, s); s = fmaf(q2.w, e2.w, s);
        s = fmaf(q3.x, e3.x, s); s = fmaf(q3.y, e3.y, s); s = fmaf(q3.z, e3.z, s); s = fmaf(q3.w, e3.w, s);
        s2 = fmaf(p0.x, e0.x, s2); s2 = fmaf(p0.y, e0.y, s2); s2 = fmaf(p0.z, e0.z, s2); s2 = fmaf(p0.w, e0.w, s2);
        s2 = fmaf(p1.x, e1.x, s2); s2 = fmaf(p1.y, e1.y, s2); s2 = fmaf(p1.z, e1.z, s2); s2 = fmaf(p1.w, e1.w, s2);
        s2 = fmaf(p2.x, e2.x, s2); s2 = fmaf(p2.y, e2.y, s2); s2 = fmaf(p2.z, e2.z, s2); s2 = fmaf(p2.w, e2.w, s2);
        s2 = fmaf(p3.x, e3.x, s2); s2 = fmaf(p3.y, e3.y, s2); s2 = fmaf(p3.z, e3.z, s2); s2 = fmaf(p3.w, e3.w, s2);
        s  += __shfl_xor(s, 1, 64);  s  += __shfl_xor(s, 2, 64);
        s2 += __shfl_xor(s2, 1, 64); s2 += __shfl_xor(s2, 2, 64);
        if (part == 0) { sb[wv][j] = s; sa[wv][j] = s2; }
    }
    float sv0 = sb[wv][lane],      av0 = sa[wv][lane];
    float sv1 = sb[wv][64 + lane], av1 = sa[wv][64 + lane];

    // top-5 over 128 via two-local admissible argmax + payload
    float prevv = INFINITY; int previ = -1;
    int cI[KTOP]; float atk[KTOP];
#pragma unroll
    for (int k = 0; k < KTOP; ++k) {
        bool adm0 = (sv0 < prevv) || (sv0 == prevv && ci0 > previ);
        bool adm1 = (sv1 < prevv) || (sv1 == prevv && ci1 > previ);
        float bv = adm0 ? sv0 : -INFINITY;
        int   bi = adm0 ? ci0 : 0x7fffffff;
        float ba = av0;
        if (adm1 && (sv1 > bv || (sv1 == bv && ci1 < bi))) { bv = sv1; bi = ci1; ba = av1; }
#pragma unroll
        for (int off = 1; off < 64; off <<= 1) {
            float ov = __shfl_xor(bv, off, 64);
            int   oi = __shfl_xor(bi, off, 64);
            float oa = __shfl_xor(ba, off, 64);
            if (ov > bv || (ov == bv && oi < bi)) { bv = ov; bi = oi; ba = oa; }
        }
        cI[k] = bi; atk[k] = ba; prevv = bv; previ = bi;
    }

    float sc[KTOP];
#pragma unroll
    for (int k = 0; k < KTOP; ++k) sc[k] = atk[k] * 0.0625f;   // 1/sqrt(256)
    float mx = sc[0];
#pragma unroll
    for (int k = 1; k < KTOP; ++k) mx = fmaxf(mx, sc[k]);
    float wgt[KTOP], ssum = 0.f;
#pragma unroll
    for (int k = 0; k < KTOP; ++k) { wgt[k] = expf(sc[k] - mx); ssum += wgt[k]; }
    float inv = 1.f / ssum;

    float mm = 0.f;
#pragma unroll
    for (int k = 0; k < KTOP; ++k)
        mm = fmaf(wgt[k] * inv, ego2[(size_t)cI[k] * EDIM + lane], mm);
    m[(size_t)r * EDIM + lane] = mm;
}

// ================================================================ att_out = m @ Wv^T + bv (R1/R11-validated)
__global__ __launch_bounds__(TPB, 3) void gemm_kernel(
        const float* __restrict__ A, const float* __restrict__ W,
        const float* __restrict__ b, float* __restrict__ out) {
    __shared__ __align__(16) float smem[64 * 64 + 128 * 64];
    float* As = smem;
    float* Bs = smem + 4096;
    int t = threadIdx.x, tx = t & 15, ty = t >> 4;
    int r0 = blockIdx.x * 64, d0 = blockIdx.y * 128;
    {
        int r = t & 63, eb = (t >> 6) * 16;
#pragma unroll
        for (int rep = 0; rep < 4; ++rep) {
            int e0 = eb + rep * 4;
            float4 v = *(const float4*)&A[(r0 + r) * EDIM + e0];
            As[(e0 + 0) * 64 + r] = v.x; As[(e0 + 1) * 64 + r] = v.y;
            As[(e0 + 2) * 64 + r] = v.z; As[(e0 + 3) * 64 + r] = v.w;
        }
    }
    {
        int d = t & 127, eb = (t >> 7) * 32;
#pragma unroll
        for (int rep = 0; rep < 8; ++rep) {
            int e0 = eb + rep * 4;
            float4 v = *(const float4*)&W[(d0 + d) * EDIM + e0];
            Bs[(e0 + 0) * 128 + d] = v.x; Bs[(e0 + 1) * 128 + d] = v.y;
            Bs[(e0 + 2) * 128 + d] = v.z; Bs[(e0 + 3) * 128 + d] = v.w;
        }
    }
    __syncthreads();
    float acc[4][8];
#pragma unroll
    for (int i = 0; i < 4; ++i)
#pragma unroll
        for (int j = 0; j < 8; ++j) acc[i][j] = 0.f;
#pragma unroll 4
    for (int e = 0; e < 64; ++e) {
        float4 a  = *(const float4*)&As[e * 64 + ty * 4];
        float4 b0 = *(const float4*)&Bs[e * 128 + tx * 4];
        float4 b1 = *(const float4*)&Bs[e * 128 + 64 + tx * 4];
        float ar[4] = {a.x, a.y, a.z, a.w};
#pragma unroll
        for (int i = 0; i < 4; ++i) {
            acc[i][0] = fmaf(ar[i], b0.x, acc[i][0]);
            acc[i][1] = fmaf(ar[i], b0.y, acc[i][1]);
            acc[i][2] = fmaf(ar[i], b0.z, acc[i][2]);
            acc[i][3] = fmaf(ar[i], b0.w, acc[i][3]);
            acc[i][4] = fmaf(ar[i], b1.x, acc[i][4]);
            acc[i][5] = fmaf(ar[i], b1.y, acc[i][5]);
            acc[i][6] = fmaf(ar[i], b1.z, acc[i][6]);
            acc[i][7] = fmaf(ar[i], b1.w, acc[i][7]);
        }
    }
    float4 bias0 = *(const float4*)&b[d0 + tx * 4];
    float4 bias1 = *(const float4*)&b[d0 + 64 + tx * 4];
#pragma unroll
    for (int i = 0; i < 4; ++i) {
        int r = r0 + ty * 4 + i;
        float4 o0 = make_float4(acc[i][0] + bias0.x, acc[i][1] + bias0.y,
                                acc[i][2] + bias0.z, acc[i][3] + bias0.w);
        float4 o1 = make_float4(acc[i][4] + bias1.x, acc[i][5] + bias1.y,
                                acc[i][6] + bias1.z, acc[i][7] + bias1.w);
        *(float4*)&out[r * DQK + d0 + tx * 4] = o0;
        *(float4*)&out[r * DQK + d0 + 64 + tx * 4] = o1;
    }
}

// ================================================================ launch
extern "C" void kernel_launch(void* const* d_in, const int* in_sizes, int n_in,
                              void* d_out, int out_size, void* d_ws, size_t ws_size,
                              hipStream_t stream) {
    const float* user  = (const float*)d_in[0];
    const float* item  = (const float*)d_in[1];
    const int*   nrows = (const int*)d_in[2];
    const int*   ncols = (const int*)d_in[3];
    const float* nvals = (const float*)d_in[4];
    const int*   arows = (const int*)d_in[5];
    const int*   acols = (const int*)d_in[6];
    const float* Wq = (const float*)d_in[8];  const float* bq = (const float*)d_in[9];
    const float* Wk = (const float*)d_in[10];
    const float* Wv = (const float*)d_in[12]; const float* bvp = (const float*)d_in[13];
    float* out = (float*)d_out;
    float* ws  = (float*)d_ws;

    const int NE = NN * EDIM;              // 393216
    float* ego1 = ws;
    float* ego2 = ws + NE;
    float* Qm   = ws + 2 * NE;
    int*   pidx = (int*)(ws + 3 * NE);     // NN*128 ints = 2*NE
    float* m    = ws + 5 * NE;
    float* Gbuf = ws + 6 * NE;             // 4160 floats
    int*   ell  = (int*)(ws + 6 * NE + 4160);
    int* cnt_n  = ell;                     // 6144
    int* cnt_a  = ell + 6144;              // 6144
    long long* cv_n = (long long*)(ell + 12288);   // NN*ELLW x 8B
    int* cv_a   = (int*)(cv_n + NN * ELLW);        // NN*ELLW x 4B

    hipMemsetAsync(cnt_n, 0, 12288 * sizeof(int), stream);
    build_kernel<<<NBUILD + 17, TPB, 0, stream>>>(nrows, ncols, nvals, arows, acols,
                                                  Wq, Wk, bq,
                                                  cnt_n, cnt_a, cv_n, cv_a, Gbuf);
    spmm_ell_emb_kernel<<<NN / 4, TPB, 0, stream>>>(cnt_n, cv_n, user, item, ego1);
    spmm_ell_kernel<<<NN / 4, TPB, 0, stream>>>(cnt_n, cv_n, ego1, ego2);
    qm_mean_kernel<<<NN / 4, TPB, 0, stream>>>(cnt_a, cv_a, ego2, ego1, user, item, Qm, out);
    topk_kernel<<<96 * SPLITS, TPB, 0, stream>>>(ego2, Qm, pidx);
    attn_sel_kernel<<<NN / 4, TPB, 0, stream>>>(Qm, ego2, pidx, Gbuf, m);
    gemm_kernel<<<dim3(NN / 64, DQK / 128), TPB, 0, stream>>>(m, Wv, bvp, out + NE);
}